// Round 12
// baseline (328.450 us; speedup 1.0000x reference)
//
#include <hip/hip_runtime.h>
#include <stdint.h>

#define B_ 2
#define S_ 2048
#define E_ 2048
#define H_ 16
#define KV_ 4
#define D_ 128
#define G_ (H_ / KV_)
#define M_ (B_ * S_)   // 4096 rows (b*s)
#define NQKV 3072      // Q 2048 | K 512 | V 512 (concatenated projection)

typedef unsigned short u16;
typedef unsigned int u32;
typedef __bf16 bf16x8 __attribute__((ext_vector_type(8)));
typedef float f32x4 __attribute__((ext_vector_type(4)));

__device__ __forceinline__ u16 f2bf(float f) {
  __bf16 h = (__bf16)f;            // v_cvt RNE
  return *(u16*)&h;
}
__device__ __forceinline__ float bf2f(u16 x) {
  return __uint_as_float(((u32)x) << 16);
}

// async global->LDS, 16B per lane; LDS dest = wave-uniform base + lane*16
__device__ __forceinline__ void gload_lds16(const u16* g, u16* lds) {
  __builtin_amdgcn_global_load_lds((const __attribute__((address_space(1))) u32*)g,
                                   (__attribute__((address_space(3))) u32*)lds,
                                   16, 0, 0);
}

// ---------------- RoPE trig table: trig[s*64+d] = (cos, sin)(s * 10000^(-d/64)) ----------------
__global__ __launch_bounds__(256) void build_trig(float2* __restrict__ tbl) {
  int i = blockIdx.x * 256 + threadIdx.x;        // [0, 2048*64)
  if (i >= S_ * 64) return;
  int d = i & 63, s = i >> 6;
  float ang = (float)s * expf(-0.14391156831212787f * (float)d);
  float sn, cs;
  sincosf(ang, &sn, &cs);
  tbl[i] = make_float2(cs, sn);
}

// ---------------- elementwise fp32 -> bf16 ----------------
__global__ __launch_bounds__(256) void convert_fp32_bf16(const float4* __restrict__ x,
                                                         uint2* __restrict__ o, int n4) {
  int i = blockIdx.x * 256 + threadIdx.x;
  if (i >= n4) return;
  float4 v = x[i];
  uint2 r;
  r.x = (u32)f2bf(v.x) | ((u32)f2bf(v.y) << 16);
  r.y = (u32)f2bf(v.z) | ((u32)f2bf(v.w) << 16);
  o[i] = r;
}

// ---------------- all 4 weights (K x N) fp32 -> (N x K) bf16, one launch ----------------
__global__ __launch_bounds__(256) void transpose_conv_all(const float* __restrict__ Wq,
                                                          const float* __restrict__ Wk,
                                                          const float* __restrict__ Wv,
                                                          const float* __restrict__ Wo,
                                                          u16* __restrict__ WqT,
                                                          u16* __restrict__ WkT,
                                                          u16* __restrict__ WvT,
                                                          u16* __restrict__ WoT) {
  __shared__ float tile[32][33];
  int bx = blockIdx.x;
  const float* W;
  u16* Wt;
  int Ndim, nx;
  if (bx < 64)       { W = Wq; Wt = WqT; Ndim = 2048; nx = bx; }
  else if (bx < 80)  { W = Wk; Wt = WkT; Ndim = 512;  nx = bx - 64; }
  else if (bx < 96)  { W = Wv; Wt = WvT; Ndim = 512;  nx = bx - 80; }
  else               { W = Wo; Wt = WoT; Ndim = 2048; nx = bx - 96; }
  int n0 = nx * 32, k0 = blockIdx.y * 32;
  int tx = threadIdx.x, ty = threadIdx.y;
#pragma unroll
  for (int i = 0; i < 4; i++) {
    int r = ty + i * 8;
    tile[r][tx] = W[(size_t)(k0 + r) * Ndim + n0 + tx];
  }
  __syncthreads();
#pragma unroll
  for (int i = 0; i < 4; i++) {
    int r = ty + i * 8;
    Wt[(size_t)(n0 + r) * 2048 + k0 + tx] = f2bf(tile[tx][r]);
  }
}

// ---------------- V cols of QKVb -> Vt [B][KV][D][S] (bf16) ----------------
__global__ __launch_bounds__(256) void transpose_v(const u16* __restrict__ QKV,
                                                   u16* __restrict__ Vt) {
  __shared__ u16 tile[32][33];
  int bkv = blockIdx.z;
  int b = bkv / KV_, kv = bkv % KV_;
  int s0 = blockIdx.x * 32, d0 = blockIdx.y * 32;
  int tx = threadIdx.x, ty = threadIdx.y;
#pragma unroll
  for (int i = 0; i < 4; i++) {
    int r = ty + i * 8;  // s within tile
    tile[r][tx] = QKV[(size_t)(b * S_ + s0 + r) * NQKV + 2560 + kv * D_ + d0 + tx];
  }
  __syncthreads();
#pragma unroll
  for (int i = 0; i < 4; i++) {
    int r = ty + i * 8;  // d within tile
    Vt[((size_t)(b * KV_ + kv) * D_ + d0 + r) * S_ + s0 + tx] = tile[tx][r];
  }
}

// ---------------- RoPE K (table) + repack K-cols of QKVb -> [b][kv][s][128] ----------------
__global__ __launch_bounds__(256) void rope_k_repack(const u16* __restrict__ QKV,
                                                     u16* __restrict__ Kp,
                                                     const float2* __restrict__ tbl,
                                                     int total) {
  int idx = blockIdx.x * 256 + threadIdx.x;
  if (idx >= total) return;
  int d = idx & 63;
  int rem = idx >> 6;
  int kv = rem & (KV_ - 1);
  int row = rem >> 2;
  int b = row >> 11;           // row / S_
  int spos = row & (S_ - 1);
  size_t src = (size_t)row * NQKV + 2048 + kv * D_ + d;
  float x0 = bf2f(QKV[src]);
  float x1 = bf2f(QKV[src + 64]);
  float2 t = tbl[(spos << 6) + d];
  size_t dst = ((size_t)((b * KV_ + kv) * S_ + spos)) * D_ + d;
  Kp[dst]      = f2bf(x0 * t.x - x1 * t.y);
  Kp[dst + 64] = f2bf(x1 * t.x + x0 * t.y);
}

// ---------------- RoPE Q in place (table) + fold 1/sqrt(D): Q cols of QKVb ----------------
__global__ __launch_bounds__(256) void rope_q_inplace(u16* __restrict__ QKV,
                                                      const float2* __restrict__ tbl,
                                                      int total) {
  int idx = blockIdx.x * 256 + threadIdx.x;
  if (idx >= total) return;
  int d = idx & 63;
  int rem = idx >> 6;
  int h = rem & (H_ - 1);
  int row = rem >> 4;
  int spos = row & (S_ - 1);
  size_t base = (size_t)row * NQKV + h * D_ + d;
  float x0 = bf2f(QKV[base]);
  float x1 = bf2f(QKV[base + 64]);
  float2 t = tbl[(spos << 6) + d];
  const float scale = 0.08838834764831845f;   // 1/sqrt(128)
  QKV[base]      = f2bf((x0 * t.x - x1 * t.y) * scale);
  QKV[base + 64] = f2bf((x1 * t.x + x0 * t.y) * scale);
}

// =====================================================================
// 256x192 4-phase bf16 GEMM for the fused QKV projection (verified r9).
// =====================================================================
__global__ __launch_bounds__(512, 2) void gemm256x192_qkv(const u16* __restrict__ A,
                                                          const u16* __restrict__ Bt,
                                                          u16* __restrict__ C) {
  extern __shared__ __align__(16) u16 smem[];   // 57344 u16 = 112 KiB
  const int Kdim = 2048;
  const int m0 = blockIdx.y * 256, n0 = blockIdx.x * 192;
  const int tid  = threadIdx.x;
  const int lane = tid & 63;
  const int wave = tid >> 6;          // 0..7
  const int wm   = wave >> 2;         // 0..1  M-half
  const int wn   = wave & 3;          // 0..3  N-quarter (48 cols each)
  const int quad = lane >> 4, lm = lane & 15;

  int soffA[2], sldbA[2];
#pragma unroll
  for (int i = 0; i < 2; i++) {
    int cc  = i * 512 + tid;
    int row = cc >> 3;
    int q   = (cc & 7) ^ (row & 7);
    soffA[i] = row * Kdim + q * 8;
    sldbA[i] = (i * 512 + wave * 64) * 8;
  }
  const int rowB = tid >> 3;
  const int soffB = rowB * Kdim + (((tid & 7) ^ (rowB & 7)) * 8);
  const int sldbB = wave * 512;
  auto STAGE_A = [&](const u16* g, u16* l) {
    gload_lds16(g + soffA[0], l + sldbA[0]);
    gload_lds16(g + soffA[1], l + sldbA[1]);
  };
  auto STAGE_B = [&](const u16* g, u16* l) {
    gload_lds16(g + soffB, l + sldbB);
  };

  int cs0 = ((0 + quad) ^ (lm & 7)) * 8;
  int cs1 = ((4 + quad) ^ (lm & 7)) * 8;

  const u16* Ag = A  + (size_t)m0 * Kdim;
  const u16* Bg = Bt + (size_t)n0 * Kdim;
  const size_t hstepA = (size_t)128 * Kdim;
  const size_t tstepB = (size_t)64 * Kdim;

  f32x4 acc[8][3];
  f32x4 zero = {0.f, 0.f, 0.f, 0.f};
#pragma unroll
  for (int m = 0; m < 8; m++)
#pragma unroll
    for (int n = 0; n < 3; n++) acc[m][n] = zero;

  int bthird[3], brow[3];
#pragma unroll
  for (int nt = 0; nt < 3; nt++) {
    int R = wn * 48 + nt * 16;
    bthird[nt] = R >> 6;
    brow[nt] = (R & 63) + lm;
  }

  const int NKT = Kdim >> 6;   // 32

  STAGE_B(Bg,                    smem + 32768 + 0 * 4096);
  STAGE_A(Ag,                    smem + 0 * 8192);
  STAGE_A(Ag + hstepA,           smem + 1 * 8192);
  STAGE_B(Bg + tstepB,           smem + 32768 + 1 * 4096);
  STAGE_B(Bg + 2 * tstepB,       smem + 32768 + 2 * 4096);
  STAGE_B(Bg + 64,               smem + 32768 + 3 * 4096);
  STAGE_A(Ag + 64,               smem + 2 * 8192);
  STAGE_A(Ag + hstepA + 64,      smem + 3 * 8192);
  asm volatile("s_waitcnt vmcnt(5)" ::: "memory");
  __builtin_amdgcn_s_barrier();

  for (int kt = 0; kt < NKT; ++kt) {
    const int cur = kt & 1;
    const u16* regA  = smem + (cur * 2 + wm) * 8192;
    const u16* regB3 = smem + 32768 + cur * 3 * 4096;
    bf16x8 af[4][2], bf[3][2];

    // ---------- phase 0 ----------
#pragma unroll
    for (int nt = 0; nt < 3; nt++) {
      const u16* p = regB3 + bthird[nt] * 4096 + brow[nt] * 64;
      bf[nt][0] = *(const bf16x8*)(p + cs0);
      bf[nt][1] = *(const bf16x8*)(p + cs1);
    }
#pragma unroll
    for (int m = 0; m < 4; m++) {
      af[m][0] = *(const bf16x8*)(regA + (m * 16 + lm) * 64 + cs0);
      af[m][1] = *(const bf16x8*)(regA + (m * 16 + lm) * 64 + cs1);
    }
    if (kt + 1 < NKT) {
      const u16* bn = Bg + (size_t)(kt + 1) * 64;
      u16* sb = smem + 32768 + ((cur ^ 1) * 3) * 4096;
      STAGE_B(bn + tstepB,     sb + 1 * 4096);
      STAGE_B(bn + 2 * tstepB, sb + 2 * 4096);
    }
    asm volatile("s_waitcnt lgkmcnt(0)" ::: "memory");
    __builtin_amdgcn_s_barrier();
    __builtin_amdgcn_s_setprio(1);
#pragma unroll
    for (int m = 0; m < 4; m++)
#pragma unroll
      for (int n = 0; n < 2; n++) {
        acc[m][n] = __builtin_amdgcn_mfma_f32_16x16x32_bf16(af[m][0], bf[n][0], acc[m][n], 0, 0, 0);
        acc[m][n] = __builtin_amdgcn_mfma_f32_16x16x32_bf16(af[m][1], bf[n][1], acc[m][n], 0, 0, 0);
      }
    __builtin_amdgcn_s_setprio(0);
    __builtin_amdgcn_s_barrier();

    // ---------- phase 1 ----------
    if (kt + 2 < NKT)
      STAGE_B(Bg + (size_t)(kt + 2) * 64, smem + 32768 + (cur * 3 + 0) * 4096);
    __builtin_amdgcn_s_barrier();
    __builtin_amdgcn_s_setprio(1);
#pragma unroll
    for (int m = 0; m < 4; m++) {
      acc[m][2] = __builtin_amdgcn_mfma_f32_16x16x32_bf16(af[m][0], bf[2][0], acc[m][2], 0, 0, 0);
      acc[m][2] = __builtin_amdgcn_mfma_f32_16x16x32_bf16(af[m][1], bf[2][1], acc[m][2], 0, 0, 0);
    }
    __builtin_amdgcn_s_setprio(0);
    __builtin_amdgcn_s_barrier();

    // ---------- phase 2 ----------
#pragma unroll
    for (int m = 0; m < 4; m++) {
      af[m][0] = *(const bf16x8*)(regA + ((m + 4) * 16 + lm) * 64 + cs0);
      af[m][1] = *(const bf16x8*)(regA + ((m + 4) * 16 + lm) * 64 + cs1);
    }
    asm volatile("s_waitcnt lgkmcnt(0)" ::: "memory");
    __builtin_amdgcn_s_barrier();
    __builtin_amdgcn_s_setprio(1);
#pragma unroll
    for (int m = 0; m < 4; m++)
#pragma unroll
      for (int n = 0; n < 2; n++) {
        acc[m + 4][n] = __builtin_amdgcn_mfma_f32_16x16x32_bf16(af[m][0], bf[n][0], acc[m + 4][n], 0, 0, 0);
        acc[m + 4][n] = __builtin_amdgcn_mfma_f32_16x16x32_bf16(af[m][1], bf[n][1], acc[m + 4][n], 0, 0, 0);
      }
    __builtin_amdgcn_s_setprio(0);
    __builtin_amdgcn_s_barrier();

    // ---------- phase 3 ----------
    if (kt + 2 < NKT) {
      STAGE_A(Ag + (size_t)(kt + 2) * 64,          smem + (cur * 2 + 0) * 8192);
      STAGE_A(Ag + hstepA + (size_t)(kt + 2) * 64, smem + (cur * 2 + 1) * 8192);
    }
    __builtin_amdgcn_s_setprio(1);
#pragma unroll
    for (int m = 0; m < 4; m++) {
      acc[m + 4][2] = __builtin_amdgcn_mfma_f32_16x16x32_bf16(af[m][0], bf[2][0], acc[m + 4][2], 0, 0, 0);
      acc[m + 4][2] = __builtin_amdgcn_mfma_f32_16x16x32_bf16(af[m][1], bf[2][1], acc[m + 4][2], 0, 0, 0);
    }
    __builtin_amdgcn_s_setprio(0);
    asm volatile("s_waitcnt vmcnt(5)" ::: "memory");
    __builtin_amdgcn_s_barrier();
  }

#pragma unroll
  for (int m = 0; m < 8; m++) {
    const int row = m0 + wm * 128 + m * 16 + quad * 4;
#pragma unroll
    for (int n = 0; n < 3; n++) {
      const int col = n0 + wn * 48 + n * 16 + lm;
#pragma unroll
      for (int r = 0; r < 4; r++)
        C[(size_t)(row + r) * NQKV + col] = f2bf(acc[m][n][r]);
    }
  }
}

// =====================================================================
// 256x128-tile GEMM for Wo (verified round 8): grid (16,16) = 256 blocks.
// =====================================================================
__global__ __launch_bounds__(512, 2) void gemm256x128_wo(const u16* __restrict__ A,
                                                         const u16* __restrict__ Bt,
                                                         float* __restrict__ C) {
  extern __shared__ __align__(16) u16 smem[];   // 49152 u16 = 96 KiB
  const int Kdim = 2048, Ndim = 2048;
  const int m0 = blockIdx.y * 256, n0 = blockIdx.x * 128;
  const int tid  = threadIdx.x;
  const int lane = tid & 63;
  const int wave = tid >> 6;          // 0..7
  const int wm   = wave >> 2;
  const int wn   = wave & 3;
  const int bh   = wn >> 1;
  const int nb   = (wn & 1) * 32;
  const int quad = lane >> 4, lm = lane & 15;

  int soffA[2], sldbA[2];
#pragma unroll
  for (int i = 0; i < 2; i++) {
    int cc  = i * 512 + tid;
    int row = cc >> 3;
    int q   = (cc & 7) ^ (row & 7);
    soffA[i] = row * Kdim + q * 8;
    sldbA[i] = (i * 512 + wave * 64) * 8;
  }
  const int rowB = tid >> 3;
  const int soffB = rowB * Kdim + (((tid & 7) ^ (rowB & 7)) * 8);
  const int sldbB = wave * 512;
  auto STAGE_A = [&](const u16* g, u16* l) {
    gload_lds16(g + soffA[0], l + sldbA[0]);
    gload_lds16(g + soffA[1], l + sldbA[1]);
  };
  auto STAGE_B = [&](const u16* g, u16* l) {
    gload_lds16(g + soffB, l + sldbB);
  };

  int cs0 = ((0 + quad) ^ (lm & 7)) * 8;
  int cs1 = ((4 + quad) ^ (lm & 7)) * 8;

  const u16* Ag = A  + (size_t)m0 * Kdim;
  const u16* Bg = Bt + (size_t)n0 * Kdim;
  const size_t hstepA = (size_t)128 * Kdim;
  const size_t hstepB = (size_t)64 * Kdim;

  f32x4 acc[8][2];
  f32x4 zero = {0.f, 0.f, 0.f, 0.f};
#pragma unroll
  for (int m = 0; m < 8; m++) {
    acc[m][0] = zero;
    acc[m][1] = zero;
  }

  const int NKT = Kdim >> 6;   // 32

  STAGE_B(Bg,              smem + 32768 + 0 * 4096);
  STAGE_A(Ag,              smem + 0 * 8192);
  STAGE_A(Ag + hstepA,     smem + 1 * 8192);
  STAGE_B(Bg + hstepB,     smem + 32768 + 1 * 4096);
  STAGE_B(Bg + 64,         smem + 32768 + 2 * 4096);
  STAGE_A(Ag + 64,         smem + 2 * 8192);
  STAGE_A(Ag + hstepA + 64, smem + 3 * 8192);
  asm volatile("s_waitcnt vmcnt(5)" ::: "memory");
  __builtin_amdgcn_s_barrier();

  for (int kt = 0; kt < NKT; ++kt) {
    const int cur = kt & 1;
    const u16* regA = smem + (cur * 2 + wm) * 8192;
    const u16* regB = smem + 32768 + (cur * 2 + bh) * 4096;
    bf16x8 af[4][2], bf[2][2];

    // ---------- phase 0 ----------
#pragma unroll
    for (int n = 0; n < 2; n++) {
      bf[n][0] = *(const bf16x8*)(regB + (nb + n * 16 + lm) * 64 + cs0);
      bf[n][1] = *(const bf16x8*)(regB + (nb + n * 16 + lm) * 64 + cs1);
    }
#pragma unroll
    for (int m = 0; m < 4; m++) {
      af[m][0] = *(const bf16x8*)(regA + (m * 16 + lm) * 64 + cs0);
      af[m][1] = *(const bf16x8*)(regA + (m * 16 + lm) * 64 + cs1);
    }
    if (kt + 1 < NKT)
      STAGE_B(Bg + hstepB + (size_t)(kt + 1) * 64,
              smem + 32768 + (((kt + 1) & 1) * 2 + 1) * 4096);
    asm volatile("s_waitcnt lgkmcnt(0)" ::: "memory");
    __builtin_amdgcn_s_barrier();
    __builtin_amdgcn_s_setprio(1);
#pragma unroll
    for (int m = 0; m < 2; m++)
#pragma unroll
      for (int n = 0; n < 2; n++) {
        acc[m][n] = __builtin_amdgcn_mfma_f32_16x16x32_bf16(af[m][0], bf[n][0], acc[m][n], 0, 0, 0);
        acc[m][n] = __builtin_amdgcn_mfma_f32_16x16x32_bf16(af[m][1], bf[n][1], acc[m][n], 0, 0, 0);
      }
    __builtin_amdgcn_s_setprio(0);
    __builtin_amdgcn_s_barrier();

    // ---------- phase 1 ----------
    if (kt + 2 < NKT)
      STAGE_B(Bg + (size_t)(kt + 2) * 64, smem + 32768 + (cur * 2 + 0) * 4096);
    __builtin_amdgcn_s_barrier();
    __builtin_amdgcn_s_setprio(1);
#pragma unroll
    for (int m = 2; m < 4; m++)
#pragma unroll
      for (int n = 0; n < 2; n++) {
        acc[m][n] = __builtin_amdgcn_mfma_f32_16x16x32_bf16(af[m][0], bf[n][0], acc[m][n], 0, 0, 0);
        acc[m][n] = __builtin_amdgcn_mfma_f32_16x16x32_bf16(af[m][1], bf[n][1], acc[m][n], 0, 0, 0);
      }
    __builtin_amdgcn_s_setprio(0);
    __builtin_amdgcn_s_barrier();

    // ---------- phase 2 ----------
#pragma unroll
    for (int m = 0; m < 4; m++) {
      af[m][0] = *(const bf16x8*)(regA + ((m + 4) * 16 + lm) * 64 + cs0);
      af[m][1] = *(const bf16x8*)(regA + ((m + 4) * 16 + lm) * 64 + cs1);
    }
    asm volatile("s_waitcnt lgkmcnt(0)" ::: "memory");
    __builtin_amdgcn_s_barrier();
    __builtin_amdgcn_s_setprio(1);
#pragma unroll
    for (int m = 0; m < 2; m++)
#pragma unroll
      for (int n = 0; n < 2; n++) {
        acc[m + 4][n] = __builtin_amdgcn_mfma_f32_16x16x32_bf16(af[m][0], bf[n][0], acc[m + 4][n], 0, 0, 0);
        acc[m + 4][n] = __builtin_amdgcn_mfma_f32_16x16x32_bf16(af[m][1], bf[n][1], acc[m + 4][n], 0, 0, 0);
      }
    __builtin_amdgcn_s_setprio(0);
    __builtin_amdgcn_s_barrier();

    // ---------- phase 3 ----------
    if (kt + 2 < NKT) {
      STAGE_A(Ag + (size_t)(kt + 2) * 64,          smem + (cur * 2 + 0) * 8192);
      STAGE_A(Ag + hstepA + (size_t)(kt + 2) * 64, smem + (cur * 2 + 1) * 8192);
    }
    __builtin_amdgcn_s_setprio(1);
#pragma unroll
    for (int m = 2; m < 4; m++)
#pragma unroll
      for (int n = 0; n < 2; n++) {
        acc[m + 4][n] = __builtin_amdgcn_mfma_f32_16x16x32_bf16(af[m][0], bf[n][0], acc[m + 4][n], 0, 0, 0);
        acc[m + 4][n] = __builtin_amdgcn_mfma_f32_16x16x32_bf16(af[m][1], bf[n][1], acc[m + 4][n], 0, 0, 0);
      }
    __builtin_amdgcn_s_setprio(0);
    asm volatile("s_waitcnt vmcnt(5)" ::: "memory");
    __builtin_amdgcn_s_barrier();
  }

#pragma unroll
  for (int m = 0; m < 8; m++) {
    const int row = m0 + wm * 128 + m * 16 + quad * 4;
#pragma unroll
    for (int n = 0; n < 2; n++) {
      const int col = n0 + wn * 32 + n * 16 + lm;
#pragma unroll
      for (int r = 0; r < 4; r++)
        C[(size_t)(row + r) * Ndim + col] = acc[m][n][r];
    }
  }
}

// ---------------- causal GQA flash attention, v14: uniform blocks + true 2x concurrency ----------------
// v13 diagnosis: pairing (qi=y with qi=15-y) balanced TOTAL work per CU but the
// short co-resident block exits immediately -> occupancy ~27% not 50%.  v14:
// every block processes TWO Q-tiles (qi = 15-y then qi = y) = (16-y)+(y+1) = 17
// units for EVERY block -> all 512 blocks equal-work, so any 2 co-resident
// blocks stay concurrent for the whole kernel: 16 waves/CU throughout.
// Inner loop = v13's verified 64 KB single-V 3-barrier counted scheme,
// byte-identical.  LDS 64 KB x 2 = 128 KB/CU (fits with slack).
__global__ __launch_bounds__(512, 4) void attn_kernel(const u16* __restrict__ Q,
                                                      const u16* __restrict__ Kp,
                                                      const u16* __restrict__ Vt,
                                                      u16* __restrict__ O) {
  __shared__ __align__(16) u16 Ksh[2][64 * 128];   // 2 x 16 KB
  __shared__ __align__(16) u16 Vsh[128 * 64];      // 16 KB (single)
  __shared__ __align__(16) u16 Psh[8][16 * 64];    // 16 KB, per-wave

  const int tid = threadIdx.x;
  const int lane = tid & 63;
  const int wave = tid >> 6;                       // 0..7
  const int quad = lane >> 4, lm = lane & 15;
  const int b = blockIdx.z, h = blockIdx.x;        // h on x for XCD locality
  const int y = blockIdx.y;                        // 0..15
  const int kh = h / G_;

  const u16* Kbase = Kp + (size_t)(b * KV_ + kh) * S_ * D_;
  const u16* Vbase = Vt + (size_t)(b * KV_ + kh) * D_ * S_;
  u16* pw = &Psh[wave][0];

  // DMA source offsets (XOR-swizzled); 1024 chunks/tile over 512 threads -> 2 each
  int offK[2], offV[2], ldsOff[2];
#pragma unroll
  for (int i = 0; i < 2; i++) {
    int idx = (wave * 2 + i) * 64 + lane;          // [0,1024) 16B-chunk id
    int rK = idx >> 4;
    int cK = (idx & 15) ^ (rK & 7);
    offK[i] = rK * 128 + cK * 8;
    int rV = idx >> 3;
    int cV = (idx & 7) ^ (rV & 7);
    offV[i] = rV * S_ + cV * 8;
    ldsOff[i] = (wave * 2 + i) * 512;
  }

  bf16x8 onesb;
#pragma unroll
  for (int j = 0; j < 8; j++) onesb[j] = (__bf16)1.0f;

#pragma unroll
  for (int half = 0; half < 2; half++) {
    const int qi = half ? y : (15 - y);            // longest first; (16-y)+(y+1) = 17 units/block
    const int sq0 = qi * 128;
    const int nT = 2 * qi + 2;                     // 64-key tiles covering sq0+128
    const int wrow = sq0 + wave * 16;              // this wave's first Q row

    // Q from QKVb cols [0,2048): row stride NQKV (RoPE+scale pre-applied)
    const u16* qptr = Q + (size_t)(b * S_ + wrow + lm) * NQKV + h * D_;
    bf16x8 qf[4];
#pragma unroll
    for (int ks = 0; ks < 4; ks++)
      qf[ks] = *(const bf16x8*)(qptr + ks * 32 + quad * 8);

    f32x4 o[8];
    f32x4 lacc = {0.f, 0.f, 0.f, 0.f};
#pragma unroll
    for (int i = 0; i < 8; i++) o[i] = f32x4{0.f, 0.f, 0.f, 0.f};

    __syncthreads();   // previous half fully done with Ksh/Vsh/Psh

    // prologue: DMA K(0) into buffer 0
#pragma unroll
    for (int i = 0; i < 2; i++)
      gload_lds16(Kbase + offK[i], &Ksh[0][ldsOff[i]]);

    for (int t = 0; t < nT; t++) {
      const int sk0 = t << 6;
      const bool act = (sk0 <= wrow + 15);         // skip fully-masked tiles

      __builtin_amdgcn_s_barrier();   // (#1) prev iter fully done: Vsh + Ksh[(t+1)&1] free

      // issue V(t) first, then K(t+1): vmcnt counts below depend on this order
#pragma unroll
      for (int i = 0; i < 2; i++)
        gload_lds16(Vbase + sk0 + offV[i], &Vsh[ldsOff[i]]);
      if (t + 1 < nT) {
        const u16* kg = Kbase + (size_t)(t + 1) * 64 * 128;
        u16* kb_next = &Ksh[(t + 1) & 1][0];
#pragma unroll
        for (int i = 0; i < 2; i++)
          gload_lds16(kg + offK[i], kb_next + ldsOff[i]);
        asm volatile("s_waitcnt vmcnt(4)" ::: "memory");  // K(t) resident (own ops)
      } else {
        asm volatile("s_waitcnt vmcnt(2)" ::: "memory");  // K(t) resident; V(t) in flight
      }

      __builtin_amdgcn_s_barrier();   // (#2) K(t) resident for ALL waves
      __builtin_amdgcn_sched_barrier(0);

      if (act) {
        // S = Q K^T (scale prefolded into Q)
        const u16* kbuf = &Ksh[t & 1][0];
        f32x4 sc[4];
#pragma unroll
        for (int nt = 0; nt < 4; nt++) sc[nt] = f32x4{0.f, 0.f, 0.f, 0.f};
        __builtin_amdgcn_s_setprio(1);
#pragma unroll
        for (int ks = 0; ks < 4; ks++) {
#pragma unroll
          for (int nt = 0; nt < 4; nt++) {
            int R = nt * 16 + lm;
            bf16x8 kb = *(const bf16x8*)(kbuf + R * 128 + (((ks * 4 + quad) ^ (R & 7)) * 8));
            sc[nt] = __builtin_amdgcn_mfma_f32_16x16x32_bf16(qf[ks], kb, sc[nt], 0, 0, 0);
          }
        }
        __builtin_amdgcn_s_setprio(0);
        // P = exp(S); causal select only on the boundary tile (wave-uniform nm)
        const bool nm = (sk0 + 63 > wrow);
#pragma unroll
        for (int nt = 0; nt < 4; nt++)
#pragma unroll
          for (int r = 0; r < 4; r++) {
            float p = __expf(sc[nt][r]);
            if (nm) {
              int kc = sk0 + nt * 16 + lm;
              int qr = wrow + quad * 4 + r;
              p = (kc > qr) ? 0.f : p;
            }
            sc[nt][r] = p;
          }
        // P: C-layout -> per-wave swizzled LDS (A-layout source for PV)
#pragma unroll
        for (int nt = 0; nt < 4; nt++)
#pragma unroll
          for (int r = 0; r < 4; r++) {
            int p = quad * 4 + r;
            int c = nt * 2 + (lm >> 3);
            pw[p * 64 + ((c ^ (p & 7)) * 8) + (lm & 7)] = f2bf(sc[nt][r]);
          }
      }

      if (t + 1 < nT) {
        asm volatile("s_waitcnt vmcnt(2)" ::: "memory");  // V(t) resident; K(t+1) in flight
      } else {
        asm volatile("s_waitcnt vmcnt(0)" ::: "memory");  // V(t) resident
      }
      __builtin_amdgcn_s_barrier();   // (#3) V(t) resident for ALL waves
      __builtin_amdgcn_sched_barrier(0);

      if (act) {
        // O += P @ V ; l += P @ ones   (per-wave Psh: within-wave lgkm dep only)
        __builtin_amdgcn_s_setprio(1);
#pragma unroll
        for (int ks = 0; ks < 2; ks++) {
          int pr = lm;
          bf16x8 pa = *(const bf16x8*)(pw + pr * 64 + (((ks * 4 + quad) ^ (pr & 7)) * 8));
          lacc = __builtin_amdgcn_mfma_f32_16x16x32_bf16(pa, onesb, lacc, 0, 0, 0);
#pragma unroll
          for (int d8 = 0; d8 < 8; d8++) {
            int R = d8 * 16 + lm;
            bf16x8 vb = *(const bf16x8*)(Vsh + R * 64 + (((ks * 4 + quad) ^ (R & 7)) * 8));
            o[d8] = __builtin_amdgcn_mfma_f32_16x16x32_bf16(pa, vb, o[d8], 0, 0, 0);
          }
        }
        __builtin_amdgcn_s_setprio(0);
      }
    }

    float inv[4];
#pragma unroll
    for (int r = 0; r < 4; r++) inv[r] = 1.0f / lacc[r];
#pragma unroll
    for (int d8 = 0; d8 < 8; d8++)
#pragma unroll
      for (int r = 0; r < 4; r++) {
        int srow = wrow + quad * 4 + r;
        O[((size_t)(b * S_ + srow) * H_ + h) * D_ + d8 * 16 + lm] = f2bf(o[d8][r] * inv[r]);
      }
  }
}

extern "C" void kernel_launch(void* const* d_in, const int* in_sizes, int n_in,
                              void* d_out, int out_size, void* d_ws, size_t ws_size,
                              hipStream_t stream) {
  const float* x  = (const float*)d_in[0];
  const float* Wq = (const float*)d_in[1];
  const float* Wk = (const float*)d_in[2];
  const float* Wv = (const float*)d_in[3];
  const float* Wo = (const float*)d_in[4];
  float* out = (float*)d_out;
  char* ws = (char*)d_ws;
  u16* Xb   = (u16*)(ws);                        // 16 MiB  bf16 x        [4096][2048]
  u16* Wcat = (u16*)(ws + (16ull << 20));        // 12 MiB  [WqT|WkT|WvT] = [3072][2048]
  u16* WqT  = Wcat;
  u16* WkT  = (u16*)(ws + (24ull << 20));
  u16* WvT  = (u16*)(ws + (26ull << 20));
  u16* WoT  = (u16*)(ws + (28ull << 20));        //  8 MiB
  u16* QKVb = (u16*)(ws + (36ull << 20));        // 24 MiB  [4096][3072]  Q|K|V proj
  u16* Vt   = (u16*)(ws + (60ull << 20));        //  4 MiB  V^T           [2][4][128][2048]
  u16* Ob   = (u16*)(ws + (64ull << 20));        // 16 MiB  attn out      [4096][16][128]
  u16* Kp   = (u16*)(ws + (80ull << 20));        //  4 MiB  K roped+packed[2][4][2048][128]
  float2* trig = (float2*)(ws + (84ull << 20));  //  1 MiB  RoPE cos/sin  [2048][64]

  static bool attr_set = false;
  if (!attr_set) {
    hipFuncSetAttribute((const void*)gemm256x192_qkv,
                        hipFuncAttributeMaxDynamicSharedMemorySize, 114688);
    hipFuncSetAttribute((const void*)gemm256x128_wo,
                        hipFuncAttributeMaxDynamicSharedMemorySize, 98304);
    attr_set = true;
  }

  dim3 tb32(32, 8);

  build_trig<<<dim3(S_ * 64 / 256), 256, 0, stream>>>(trig);

  convert_fp32_bf16<<<dim3(M_ * E_ / 4 / 256), 256, 0, stream>>>((const float4*)x, (uint2*)Xb, M_ * E_ / 4);

  transpose_conv_all<<<dim3(160, 64), tb32, 0, stream>>>(Wq, Wk, Wv, Wo, WqT, WkT, WvT, WoT);

  gemm256x192_qkv<<<dim3(16, 16), 512, 114688, stream>>>(Xb, Wcat, QKVb);

  rope_q_inplace<<<dim3(M_ * H_ * 64 / 256), 256, 0, stream>>>(QKVb, trig, M_ * H_ * 64);

  rope_k_repack<<<dim3(M_ * KV_ * 64 / 256), 256, 0, stream>>>(QKVb, Kp, trig, M_ * KV_ * 64);

  transpose_v<<<dim3(S_ / 32, D_ / 32, B_ * KV_), tb32, 0, stream>>>(QKVb, Vt);

  attn_kernel<<<dim3(H_, 16, B_), 512, 0, stream>>>(QKVb, Kp, Vt, Ob);

  gemm256x128_wo<<<dim3(2048 / 128, M_ / 256), 512, 98304, stream>>>(Ob, WoT, out);
}

// Round 13
// 274.416 us; speedup vs baseline: 1.1969x; 1.1969x over previous
//
#include <hip/hip_runtime.h>
#include <stdint.h>

#define B_ 2
#define S_ 2048
#define E_ 2048
#define H_ 16
#define KV_ 4
#define D_ 128
#define G_ (H_ / KV_)
#define M_ (B_ * S_)   // 4096 rows (b*s)
#define NQKV 3072      // Q 2048 | K 512 | V 512 (concatenated projection)

typedef unsigned short u16;
typedef unsigned int u32;
typedef __bf16 bf16x8 __attribute__((ext_vector_type(8)));
typedef float f32x4 __attribute__((ext_vector_type(4)));

__device__ __forceinline__ u16 f2bf(float f) {
  __bf16 h = (__bf16)f;            // v_cvt RNE
  return *(u16*)&h;
}
__device__ __forceinline__ float bf2f(u16 x) {
  return __uint_as_float(((u32)x) << 16);
}

// async global->LDS, 16B per lane; LDS dest = wave-uniform base + lane*16
__device__ __forceinline__ void gload_lds16(const u16* g, u16* lds) {
  __builtin_amdgcn_global_load_lds((const __attribute__((address_space(1))) u32*)g,
                                   (__attribute__((address_space(3))) u32*)lds,
                                   16, 0, 0);
}

// ---------------- RoPE trig table: trig[s*64+d] = (cos, sin)(s * 10000^(-d/64)) ----------------
__global__ __launch_bounds__(256) void build_trig(float2* __restrict__ tbl) {
  int i = blockIdx.x * 256 + threadIdx.x;        // [0, 2048*64)
  if (i >= S_ * 64) return;
  int d = i & 63, s = i >> 6;
  float ang = (float)s * expf(-0.14391156831212787f * (float)d);
  float sn, cs;
  sincosf(ang, &sn, &cs);
  tbl[i] = make_float2(cs, sn);
}

// ---------------- elementwise fp32 -> bf16 ----------------
__global__ __launch_bounds__(256) void convert_fp32_bf16(const float4* __restrict__ x,
                                                         uint2* __restrict__ o, int n4) {
  int i = blockIdx.x * 256 + threadIdx.x;
  if (i >= n4) return;
  float4 v = x[i];
  uint2 r;
  r.x = (u32)f2bf(v.x) | ((u32)f2bf(v.y) << 16);
  r.y = (u32)f2bf(v.z) | ((u32)f2bf(v.w) << 16);
  o[i] = r;
}

// ---------------- all 4 weights (K x N) fp32 -> (N x K) bf16, one launch ----------------
__global__ __launch_bounds__(256) void transpose_conv_all(const float* __restrict__ Wq,
                                                          const float* __restrict__ Wk,
                                                          const float* __restrict__ Wv,
                                                          const float* __restrict__ Wo,
                                                          u16* __restrict__ WqT,
                                                          u16* __restrict__ WkT,
                                                          u16* __restrict__ WvT,
                                                          u16* __restrict__ WoT) {
  __shared__ float tile[32][33];
  int bx = blockIdx.x;
  const float* W;
  u16* Wt;
  int Ndim, nx;
  if (bx < 64)       { W = Wq; Wt = WqT; Ndim = 2048; nx = bx; }
  else if (bx < 80)  { W = Wk; Wt = WkT; Ndim = 512;  nx = bx - 64; }
  else if (bx < 96)  { W = Wv; Wt = WvT; Ndim = 512;  nx = bx - 80; }
  else               { W = Wo; Wt = WoT; Ndim = 2048; nx = bx - 96; }
  int n0 = nx * 32, k0 = blockIdx.y * 32;
  int tx = threadIdx.x, ty = threadIdx.y;
#pragma unroll
  for (int i = 0; i < 4; i++) {
    int r = ty + i * 8;
    tile[r][tx] = W[(size_t)(k0 + r) * Ndim + n0 + tx];
  }
  __syncthreads();
#pragma unroll
  for (int i = 0; i < 4; i++) {
    int r = ty + i * 8;
    Wt[(size_t)(n0 + r) * 2048 + k0 + tx] = f2bf(tile[tx][r]);
  }
}

// ---------------- fused: RoPE K repack (table) + V transpose, one launch ----------------
// bx < 4096: rope_k elementwise over K-cols of QKVb -> Kp [b][kv][s][128]
// bx >= 4096: 32x32 LDS transpose of V-cols of QKVb -> Vt [b][kv][d][s]
// Independent reads of QKVb, disjoint outputs -> no ordering hazard.
__global__ __launch_bounds__(256) void rope_k_tv(const u16* __restrict__ QKV,
                                                 u16* __restrict__ Kp,
                                                 u16* __restrict__ Vt,
                                                 const float2* __restrict__ tbl) {
  __shared__ u16 tile[32][33];
  int bx = blockIdx.x;
  int tid = threadIdx.x;
  if (bx < 4096) {
    int idx = bx * 256 + tid;                    // [0, M_*KV_*64)
    int d = idx & 63;
    int rem = idx >> 6;
    int kv = rem & (KV_ - 1);
    int row = rem >> 2;
    int b = row >> 11;                           // row / S_
    int spos = row & (S_ - 1);
    size_t src = (size_t)row * NQKV + 2048 + kv * D_ + d;
    float x0 = bf2f(QKV[src]);
    float x1 = bf2f(QKV[src + 64]);
    float2 t = tbl[(spos << 6) + d];
    size_t dst = ((size_t)((b * KV_ + kv) * S_ + spos)) * D_ + d;
    Kp[dst]      = f2bf(x0 * t.x - x1 * t.y);
    Kp[dst + 64] = f2bf(x1 * t.x + x0 * t.y);
  } else {
    int i = bx - 4096;                           // [0, 2048)
    int s0 = (i & 63) * 32;                      // 64 s-tiles
    int d0 = ((i >> 6) & 3) * 32;                // 4 d-tiles
    int bkv = i >> 8;                            // 8 (b,kv)
    int b = bkv / KV_, kv = bkv % KV_;
    int tx = tid & 31, ty = tid >> 5;
#pragma unroll
    for (int k = 0; k < 4; k++) {
      int r = ty + k * 8;  // s within tile
      tile[r][tx] = QKV[(size_t)(b * S_ + s0 + r) * NQKV + 2560 + kv * D_ + d0 + tx];
    }
    __syncthreads();
#pragma unroll
    for (int k = 0; k < 4; k++) {
      int r = ty + k * 8;  // d within tile
      Vt[((size_t)(b * KV_ + kv) * D_ + d0 + r) * S_ + s0 + tx] = tile[tx][r];
    }
  }
}

// =====================================================================
// 256x192 4-phase bf16 GEMM for the fused QKV projection (verified r9).
// =====================================================================
__global__ __launch_bounds__(512, 2) void gemm256x192_qkv(const u16* __restrict__ A,
                                                          const u16* __restrict__ Bt,
                                                          u16* __restrict__ C) {
  extern __shared__ __align__(16) u16 smem[];   // 57344 u16 = 112 KiB
  const int Kdim = 2048;
  const int m0 = blockIdx.y * 256, n0 = blockIdx.x * 192;
  const int tid  = threadIdx.x;
  const int lane = tid & 63;
  const int wave = tid >> 6;          // 0..7
  const int wm   = wave >> 2;         // 0..1  M-half
  const int wn   = wave & 3;          // 0..3  N-quarter (48 cols each)
  const int quad = lane >> 4, lm = lane & 15;

  int soffA[2], sldbA[2];
#pragma unroll
  for (int i = 0; i < 2; i++) {
    int cc  = i * 512 + tid;
    int row = cc >> 3;
    int q   = (cc & 7) ^ (row & 7);
    soffA[i] = row * Kdim + q * 8;
    sldbA[i] = (i * 512 + wave * 64) * 8;
  }
  const int rowB = tid >> 3;
  const int soffB = rowB * Kdim + (((tid & 7) ^ (rowB & 7)) * 8);
  const int sldbB = wave * 512;
  auto STAGE_A = [&](const u16* g, u16* l) {
    gload_lds16(g + soffA[0], l + sldbA[0]);
    gload_lds16(g + soffA[1], l + sldbA[1]);
  };
  auto STAGE_B = [&](const u16* g, u16* l) {
    gload_lds16(g + soffB, l + sldbB);
  };

  int cs0 = ((0 + quad) ^ (lm & 7)) * 8;
  int cs1 = ((4 + quad) ^ (lm & 7)) * 8;

  const u16* Ag = A  + (size_t)m0 * Kdim;
  const u16* Bg = Bt + (size_t)n0 * Kdim;
  const size_t hstepA = (size_t)128 * Kdim;
  const size_t tstepB = (size_t)64 * Kdim;

  f32x4 acc[8][3];
  f32x4 zero = {0.f, 0.f, 0.f, 0.f};
#pragma unroll
  for (int m = 0; m < 8; m++)
#pragma unroll
    for (int n = 0; n < 3; n++) acc[m][n] = zero;

  int bthird[3], brow[3];
#pragma unroll
  for (int nt = 0; nt < 3; nt++) {
    int R = wn * 48 + nt * 16;
    bthird[nt] = R >> 6;
    brow[nt] = (R & 63) + lm;
  }

  const int NKT = Kdim >> 6;   // 32

  STAGE_B(Bg,                    smem + 32768 + 0 * 4096);
  STAGE_A(Ag,                    smem + 0 * 8192);
  STAGE_A(Ag + hstepA,           smem + 1 * 8192);
  STAGE_B(Bg + tstepB,           smem + 32768 + 1 * 4096);
  STAGE_B(Bg + 2 * tstepB,       smem + 32768 + 2 * 4096);
  STAGE_B(Bg + 64,               smem + 32768 + 3 * 4096);
  STAGE_A(Ag + 64,               smem + 2 * 8192);
  STAGE_A(Ag + hstepA + 64,      smem + 3 * 8192);
  asm volatile("s_waitcnt vmcnt(5)" ::: "memory");
  __builtin_amdgcn_s_barrier();

  for (int kt = 0; kt < NKT; ++kt) {
    const int cur = kt & 1;
    const u16* regA  = smem + (cur * 2 + wm) * 8192;
    const u16* regB3 = smem + 32768 + cur * 3 * 4096;
    bf16x8 af[4][2], bf[3][2];

    // ---------- phase 0 ----------
#pragma unroll
    for (int nt = 0; nt < 3; nt++) {
      const u16* p = regB3 + bthird[nt] * 4096 + brow[nt] * 64;
      bf[nt][0] = *(const bf16x8*)(p + cs0);
      bf[nt][1] = *(const bf16x8*)(p + cs1);
    }
#pragma unroll
    for (int m = 0; m < 4; m++) {
      af[m][0] = *(const bf16x8*)(regA + (m * 16 + lm) * 64 + cs0);
      af[m][1] = *(const bf16x8*)(regA + (m * 16 + lm) * 64 + cs1);
    }
    if (kt + 1 < NKT) {
      const u16* bn = Bg + (size_t)(kt + 1) * 64;
      u16* sb = smem + 32768 + ((cur ^ 1) * 3) * 4096;
      STAGE_B(bn + tstepB,     sb + 1 * 4096);
      STAGE_B(bn + 2 * tstepB, sb + 2 * 4096);
    }
    asm volatile("s_waitcnt lgkmcnt(0)" ::: "memory");
    __builtin_amdgcn_s_barrier();
    __builtin_amdgcn_s_setprio(1);
#pragma unroll
    for (int m = 0; m < 4; m++)
#pragma unroll
      for (int n = 0; n < 2; n++) {
        acc[m][n] = __builtin_amdgcn_mfma_f32_16x16x32_bf16(af[m][0], bf[n][0], acc[m][n], 0, 0, 0);
        acc[m][n] = __builtin_amdgcn_mfma_f32_16x16x32_bf16(af[m][1], bf[n][1], acc[m][n], 0, 0, 0);
      }
    __builtin_amdgcn_s_setprio(0);
    __builtin_amdgcn_s_barrier();

    // ---------- phase 1 ----------
    if (kt + 2 < NKT)
      STAGE_B(Bg + (size_t)(kt + 2) * 64, smem + 32768 + (cur * 3 + 0) * 4096);
    __builtin_amdgcn_s_barrier();
    __builtin_amdgcn_s_setprio(1);
#pragma unroll
    for (int m = 0; m < 4; m++) {
      acc[m][2] = __builtin_amdgcn_mfma_f32_16x16x32_bf16(af[m][0], bf[2][0], acc[m][2], 0, 0, 0);
      acc[m][2] = __builtin_amdgcn_mfma_f32_16x16x32_bf16(af[m][1], bf[2][1], acc[m][2], 0, 0, 0);
    }
    __builtin_amdgcn_s_setprio(0);
    __builtin_amdgcn_s_barrier();

    // ---------- phase 2 ----------
#pragma unroll
    for (int m = 0; m < 4; m++) {
      af[m][0] = *(const bf16x8*)(regA + ((m + 4) * 16 + lm) * 64 + cs0);
      af[m][1] = *(const bf16x8*)(regA + ((m + 4) * 16 + lm) * 64 + cs1);
    }
    asm volatile("s_waitcnt lgkmcnt(0)" ::: "memory");
    __builtin_amdgcn_s_barrier();
    __builtin_amdgcn_s_setprio(1);
#pragma unroll
    for (int m = 0; m < 4; m++)
#pragma unroll
      for (int n = 0; n < 2; n++) {
        acc[m + 4][n] = __builtin_amdgcn_mfma_f32_16x16x32_bf16(af[m][0], bf[n][0], acc[m + 4][n], 0, 0, 0);
        acc[m + 4][n] = __builtin_amdgcn_mfma_f32_16x16x32_bf16(af[m][1], bf[n][1], acc[m + 4][n], 0, 0, 0);
      }
    __builtin_amdgcn_s_setprio(0);
    __builtin_amdgcn_s_barrier();

    // ---------- phase 3 ----------
    if (kt + 2 < NKT) {
      STAGE_A(Ag + (size_t)(kt + 2) * 64,          smem + (cur * 2 + 0) * 8192);
      STAGE_A(Ag + hstepA + (size_t)(kt + 2) * 64, smem + (cur * 2 + 1) * 8192);
    }
    __builtin_amdgcn_s_setprio(1);
#pragma unroll
    for (int m = 0; m < 4; m++) {
      acc[m + 4][2] = __builtin_amdgcn_mfma_f32_16x16x32_bf16(af[m][0], bf[2][0], acc[m + 4][2], 0, 0, 0);
      acc[m + 4][2] = __builtin_amdgcn_mfma_f32_16x16x32_bf16(af[m][1], bf[2][1], acc[m + 4][2], 0, 0, 0);
    }
    __builtin_amdgcn_s_setprio(0);
    asm volatile("s_waitcnt vmcnt(5)" ::: "memory");
    __builtin_amdgcn_s_barrier();
  }

#pragma unroll
  for (int m = 0; m < 8; m++) {
    const int row = m0 + wm * 128 + m * 16 + quad * 4;
#pragma unroll
    for (int n = 0; n < 3; n++) {
      const int col = n0 + wn * 48 + n * 16 + lm;
#pragma unroll
      for (int r = 0; r < 4; r++)
        C[(size_t)(row + r) * NQKV + col] = f2bf(acc[m][n][r]);
    }
  }
}

// =====================================================================
// 256x128-tile GEMM for Wo (verified round 8): grid (16,16) = 256 blocks.
// =====================================================================
__global__ __launch_bounds__(512, 2) void gemm256x128_wo(const u16* __restrict__ A,
                                                         const u16* __restrict__ Bt,
                                                         float* __restrict__ C) {
  extern __shared__ __align__(16) u16 smem[];   // 49152 u16 = 96 KiB
  const int Kdim = 2048, Ndim = 2048;
  const int m0 = blockIdx.y * 256, n0 = blockIdx.x * 128;
  const int tid  = threadIdx.x;
  const int lane = tid & 63;
  const int wave = tid >> 6;          // 0..7
  const int wm   = wave >> 2;
  const int wn   = wave & 3;
  const int bh   = wn >> 1;
  const int nb   = (wn & 1) * 32;
  const int quad = lane >> 4, lm = lane & 15;

  int soffA[2], sldbA[2];
#pragma unroll
  for (int i = 0; i < 2; i++) {
    int cc  = i * 512 + tid;
    int row = cc >> 3;
    int q   = (cc & 7) ^ (row & 7);
    soffA[i] = row * Kdim + q * 8;
    sldbA[i] = (i * 512 + wave * 64) * 8;
  }
  const int rowB = tid >> 3;
  const int soffB = rowB * Kdim + (((tid & 7) ^ (rowB & 7)) * 8);
  const int sldbB = wave * 512;
  auto STAGE_A = [&](const u16* g, u16* l) {
    gload_lds16(g + soffA[0], l + sldbA[0]);
    gload_lds16(g + soffA[1], l + sldbA[1]);
  };
  auto STAGE_B = [&](const u16* g, u16* l) {
    gload_lds16(g + soffB, l + sldbB);
  };

  int cs0 = ((0 + quad) ^ (lm & 7)) * 8;
  int cs1 = ((4 + quad) ^ (lm & 7)) * 8;

  const u16* Ag = A  + (size_t)m0 * Kdim;
  const u16* Bg = Bt + (size_t)n0 * Kdim;
  const size_t hstepA = (size_t)128 * Kdim;
  const size_t hstepB = (size_t)64 * Kdim;

  f32x4 acc[8][2];
  f32x4 zero = {0.f, 0.f, 0.f, 0.f};
#pragma unroll
  for (int m = 0; m < 8; m++) {
    acc[m][0] = zero;
    acc[m][1] = zero;
  }

  const int NKT = Kdim >> 6;   // 32

  STAGE_B(Bg,              smem + 32768 + 0 * 4096);
  STAGE_A(Ag,              smem + 0 * 8192);
  STAGE_A(Ag + hstepA,     smem + 1 * 8192);
  STAGE_B(Bg + hstepB,     smem + 32768 + 1 * 4096);
  STAGE_B(Bg + 64,         smem + 32768 + 2 * 4096);
  STAGE_A(Ag + 64,         smem + 2 * 8192);
  STAGE_A(Ag + hstepA + 64, smem + 3 * 8192);
  asm volatile("s_waitcnt vmcnt(5)" ::: "memory");
  __builtin_amdgcn_s_barrier();

  for (int kt = 0; kt < NKT; ++kt) {
    const int cur = kt & 1;
    const u16* regA = smem + (cur * 2 + wm) * 8192;
    const u16* regB = smem + 32768 + (cur * 2 + bh) * 4096;
    bf16x8 af[4][2], bf[2][2];

    // ---------- phase 0 ----------
#pragma unroll
    for (int n = 0; n < 2; n++) {
      bf[n][0] = *(const bf16x8*)(regB + (nb + n * 16 + lm) * 64 + cs0);
      bf[n][1] = *(const bf16x8*)(regB + (nb + n * 16 + lm) * 64 + cs1);
    }
#pragma unroll
    for (int m = 0; m < 4; m++) {
      af[m][0] = *(const bf16x8*)(regA + (m * 16 + lm) * 64 + cs0);
      af[m][1] = *(const bf16x8*)(regA + (m * 16 + lm) * 64 + cs1);
    }
    if (kt + 1 < NKT)
      STAGE_B(Bg + hstepB + (size_t)(kt + 1) * 64,
              smem + 32768 + (((kt + 1) & 1) * 2 + 1) * 4096);
    asm volatile("s_waitcnt lgkmcnt(0)" ::: "memory");
    __builtin_amdgcn_s_barrier();
    __builtin_amdgcn_s_setprio(1);
#pragma unroll
    for (int m = 0; m < 2; m++)
#pragma unroll
      for (int n = 0; n < 2; n++) {
        acc[m][n] = __builtin_amdgcn_mfma_f32_16x16x32_bf16(af[m][0], bf[n][0], acc[m][n], 0, 0, 0);
        acc[m][n] = __builtin_amdgcn_mfma_f32_16x16x32_bf16(af[m][1], bf[n][1], acc[m][n], 0, 0, 0);
      }
    __builtin_amdgcn_s_setprio(0);
    __builtin_amdgcn_s_barrier();

    // ---------- phase 1 ----------
    if (kt + 2 < NKT)
      STAGE_B(Bg + (size_t)(kt + 2) * 64, smem + 32768 + (cur * 2 + 0) * 4096);
    __builtin_amdgcn_s_barrier();
    __builtin_amdgcn_s_setprio(1);
#pragma unroll
    for (int m = 2; m < 4; m++)
#pragma unroll
      for (int n = 0; n < 2; n++) {
        acc[m][n] = __builtin_amdgcn_mfma_f32_16x16x32_bf16(af[m][0], bf[n][0], acc[m][n], 0, 0, 0);
        acc[m][n] = __builtin_amdgcn_mfma_f32_16x16x32_bf16(af[m][1], bf[n][1], acc[m][n], 0, 0, 0);
      }
    __builtin_amdgcn_s_setprio(0);
    __builtin_amdgcn_s_barrier();

    // ---------- phase 2 ----------
#pragma unroll
    for (int m = 0; m < 4; m++) {
      af[m][0] = *(const bf16x8*)(regA + ((m + 4) * 16 + lm) * 64 + cs0);
      af[m][1] = *(const bf16x8*)(regA + ((m + 4) * 16 + lm) * 64 + cs1);
    }
    asm volatile("s_waitcnt lgkmcnt(0)" ::: "memory");
    __builtin_amdgcn_s_barrier();
    __builtin_amdgcn_s_setprio(1);
#pragma unroll
    for (int m = 0; m < 2; m++)
#pragma unroll
      for (int n = 0; n < 2; n++) {
        acc[m + 4][n] = __builtin_amdgcn_mfma_f32_16x16x32_bf16(af[m][0], bf[n][0], acc[m + 4][n], 0, 0, 0);
        acc[m + 4][n] = __builtin_amdgcn_mfma_f32_16x16x32_bf16(af[m][1], bf[n][1], acc[m + 4][n], 0, 0, 0);
      }
    __builtin_amdgcn_s_setprio(0);
    __builtin_amdgcn_s_barrier();

    // ---------- phase 3 ----------
    if (kt + 2 < NKT) {
      STAGE_A(Ag + (size_t)(kt + 2) * 64,          smem + (cur * 2 + 0) * 8192);
      STAGE_A(Ag + hstepA + (size_t)(kt + 2) * 64, smem + (cur * 2 + 1) * 8192);
    }
    __builtin_amdgcn_s_setprio(1);
#pragma unroll
    for (int m = 2; m < 4; m++)
#pragma unroll
      for (int n = 0; n < 2; n++) {
        acc[m + 4][n] = __builtin_amdgcn_mfma_f32_16x16x32_bf16(af[m][0], bf[n][0], acc[m + 4][n], 0, 0, 0);
        acc[m + 4][n] = __builtin_amdgcn_mfma_f32_16x16x32_bf16(af[m][1], bf[n][1], acc[m + 4][n], 0, 0, 0);
      }
    __builtin_amdgcn_s_setprio(0);
    asm volatile("s_waitcnt vmcnt(5)" ::: "memory");
    __builtin_amdgcn_s_barrier();
  }

#pragma unroll
  for (int m = 0; m < 8; m++) {
    const int row = m0 + wm * 128 + m * 16 + quad * 4;
#pragma unroll
    for (int n = 0; n < 2; n++) {
      const int col = n0 + wn * 32 + n * 16 + lm;
#pragma unroll
      for (int r = 0; r < 4; r++)
        C[(size_t)(row + r) * Ndim + col] = acc[m][n][r];
    }
  }
}

// ---------------- causal GQA flash attention, v15 = v13 (best verified) + in-kernel table RoPE ----------------
// v13 structure verbatim: one Q-tile per block, qi = b ? y : 15-y, 8 waves x
// 16 rows, 64 KB LDS (single-V, 3-barrier counted vmcnt scheme).  Q-RoPE is
// applied at fragment-load time from the trig TABLE (16 float2 L2-resident
// loads + 32 FMA once per block — negligible), eliminating the 32 MB
// rope_q_inplace pass entirely.  Math identical to the pass.
__global__ __launch_bounds__(512, 4) void attn_kernel(const u16* __restrict__ Q,
                                                      const u16* __restrict__ Kp,
                                                      const u16* __restrict__ Vt,
                                                      u16* __restrict__ O,
                                                      const float2* __restrict__ tbl) {
  __shared__ __align__(16) u16 Ksh[2][64 * 128];   // 2 x 16 KB
  __shared__ __align__(16) u16 Vsh[128 * 64];      // 16 KB (single)
  __shared__ __align__(16) u16 Psh[8][16 * 64];    // 16 KB, per-wave

  const int tid = threadIdx.x;
  const int lane = tid & 63;
  const int wave = tid >> 6;                       // 0..7
  const int quad = lane >> 4, lm = lane & 15;
  const int b = blockIdx.z, h = blockIdx.x;        // h on x for XCD locality
  const int y = blockIdx.y;                        // 0..15
  const int kh = h / G_;
  const int qi = b ? y : (15 - y);                 // co-residency pairing

  const u16* Kbase = Kp + (size_t)(b * KV_ + kh) * S_ * D_;
  const u16* Vbase = Vt + (size_t)(b * KV_ + kh) * D_ * S_;
  u16* pw = &Psh[wave][0];

  // DMA source offsets (XOR-swizzled); 1024 chunks/tile over 512 threads -> 2 each
  int offK[2], offV[2], ldsOff[2];
#pragma unroll
  for (int i = 0; i < 2; i++) {
    int idx = (wave * 2 + i) * 64 + lane;          // [0,1024) 16B-chunk id
    int rK = idx >> 4;
    int cK = (idx & 15) ^ (rK & 7);
    offK[i] = rK * 128 + cK * 8;
    int rV = idx >> 3;
    int cV = (idx & 7) ^ (rV & 7);
    offV[i] = rV * S_ + cV * 8;
    ldsOff[i] = (wave * 2 + i) * 512;
  }

  bf16x8 onesb;
#pragma unroll
  for (int j = 0; j < 8; j++) onesb[j] = (__bf16)1.0f;

  const int sq0 = qi * 128;
  const int nT = 2 * qi + 2;                       // 64-key tiles covering sq0+128
  const int wrow = sq0 + wave * 16;                // this wave's first Q row

  // ---- Q fragment load + fused table-RoPE + 1/sqrt(D) scale ----
  // qf[ks][j] holds dim d = ks*32 + quad*8 + j; pair (d, d+64) = (ks, ks+2)
  const int spos = wrow + lm;                      // sequence position (< S_)
  const u16* qptr = Q + (size_t)(b * S_ + spos) * NQKV + h * D_;
  bf16x8 qf[4];
#pragma unroll
  for (int ks = 0; ks < 2; ks++) {
    bf16x8 a = *(const bf16x8*)(qptr + ks * 32 + quad * 8);
    bf16x8 c = *(const bf16x8*)(qptr + (ks + 2) * 32 + quad * 8);
#pragma unroll
    for (int j = 0; j < 8; j++) {
      int d = ks * 32 + quad * 8 + j;
      float2 t = tbl[(spos << 6) + d];
      float x0 = (float)a[j], x1 = (float)c[j];
      const float scale = 0.08838834764831845f;
      qf[ks][j]     = (__bf16)((x0 * t.x - x1 * t.y) * scale);
      qf[ks + 2][j] = (__bf16)((x1 * t.x + x0 * t.y) * scale);
    }
  }

  f32x4 o[8];
  f32x4 lacc = {0.f, 0.f, 0.f, 0.f};
#pragma unroll
  for (int i = 0; i < 8; i++) o[i] = f32x4{0.f, 0.f, 0.f, 0.f};

  // prologue: DMA K(0) into buffer 0
#pragma unroll
  for (int i = 0; i < 2; i++)
    gload_lds16(Kbase + offK[i], &Ksh[0][ldsOff[i]]);

  for (int t = 0; t < nT; t++) {
    const int sk0 = t << 6;
    const bool act = (sk0 <= wrow + 15);           // skip fully-masked tiles

    __builtin_amdgcn_s_barrier();   // (#1) prev iter fully done: Vsh + Ksh[(t+1)&1] free

    // issue V(t) first, then K(t+1): vmcnt counts below depend on this order
#pragma unroll
    for (int i = 0; i < 2; i++)
      gload_lds16(Vbase + sk0 + offV[i], &Vsh[ldsOff[i]]);
    if (t + 1 < nT) {
      const u16* kg = Kbase + (size_t)(t + 1) * 64 * 128;
      u16* kb_next = &Ksh[(t + 1) & 1][0];
#pragma unroll
      for (int i = 0; i < 2; i++)
        gload_lds16(kg + offK[i], kb_next + ldsOff[i]);
      asm volatile("s_waitcnt vmcnt(4)" ::: "memory");  // K(t) resident (own ops)
    } else {
      asm volatile("s_waitcnt vmcnt(2)" ::: "memory");  // K(t) resident; V(t) in flight
    }

    __builtin_amdgcn_s_barrier();   // (#2) K(t) resident for ALL waves
    __builtin_amdgcn_sched_barrier(0);

    if (act) {
      // S = Q K^T (scale prefolded into Q)
      const u16* kbuf = &Ksh[t & 1][0];
      f32x4 sc[4];
#pragma unroll
      for (int nt = 0; nt < 4; nt++) sc[nt] = f32x4{0.f, 0.f, 0.f, 0.f};
      __builtin_amdgcn_s_setprio(1);
#pragma unroll
      for (int ks = 0; ks < 4; ks++) {
#pragma unroll
        for (int nt = 0; nt < 4; nt++) {
          int R = nt * 16 + lm;
          bf16x8 kb = *(const bf16x8*)(kbuf + R * 128 + (((ks * 4 + quad) ^ (R & 7)) * 8));
          sc[nt] = __builtin_amdgcn_mfma_f32_16x16x32_bf16(qf[ks], kb, sc[nt], 0, 0, 0);
        }
      }
      __builtin_amdgcn_s_setprio(0);
      // P = exp(S); causal select only on the boundary tile (wave-uniform nm)
      const bool nm = (sk0 + 63 > wrow);
#pragma unroll
      for (int nt = 0; nt < 4; nt++)
#pragma unroll
        for (int r = 0; r < 4; r++) {
          float p = __expf(sc[nt][r]);
          if (nm) {
            int kc = sk0 + nt * 16 + lm;
            int qr = wrow + quad * 4 + r;
            p = (kc > qr) ? 0.f : p;
          }
          sc[nt][r] = p;
        }
      // P: C-layout -> per-wave swizzled LDS (A-layout source for PV)
#pragma unroll
      for (int nt = 0; nt < 4; nt++)
#pragma unroll
        for (int r = 0; r < 4; r++) {
          int p = quad * 4 + r;
          int c = nt * 2 + (lm >> 3);
          pw[p * 64 + ((c ^ (p & 7)) * 8) + (lm & 7)] = f2bf(sc[nt][r]);
        }
    }

    if (t + 1 < nT) {
      asm volatile("s_waitcnt vmcnt(2)" ::: "memory");  // V(t) resident; K(t+1) in flight
    } else {
      asm volatile("s_waitcnt vmcnt(0)" ::: "memory");  // V(t) resident
    }
    __builtin_amdgcn_s_barrier();   // (#3) V(t) resident for ALL waves
    __builtin_amdgcn_sched_barrier(0);

    if (act) {
      // O += P @ V ; l += P @ ones   (per-wave Psh: within-wave lgkm dep only)
      __builtin_amdgcn_s_setprio(1);
#pragma unroll
      for (int ks = 0; ks < 2; ks++) {
        int pr = lm;
        bf16x8 pa = *(const bf16x8*)(pw + pr * 64 + (((ks * 4 + quad) ^ (pr & 7)) * 8));
        lacc = __builtin_amdgcn_mfma_f32_16x16x32_bf16(pa, onesb, lacc, 0, 0, 0);
#pragma unroll
        for (int d8 = 0; d8 < 8; d8++) {
          int R = d8 * 16 + lm;
          bf16x8 vb = *(const bf16x8*)(Vsh + R * 64 + (((ks * 4 + quad) ^ (R & 7)) * 8));
          o[d8] = __builtin_amdgcn_mfma_f32_16x16x32_bf16(pa, vb, o[d8], 0, 0, 0);
        }
      }
      __builtin_amdgcn_s_setprio(0);
    }
  }

  float inv[4];
#pragma unroll
  for (int r = 0; r < 4; r++) inv[r] = 1.0f / lacc[r];
#pragma unroll
  for (int d8 = 0; d8 < 8; d8++)
#pragma unroll
    for (int r = 0; r < 4; r++) {
      int srow = wrow + quad * 4 + r;
      O[((size_t)(b * S_ + srow) * H_ + h) * D_ + d8 * 16 + lm] = f2bf(o[d8][r] * inv[r]);
    }
}

extern "C" void kernel_launch(void* const* d_in, const int* in_sizes, int n_in,
                              void* d_out, int out_size, void* d_ws, size_t ws_size,
                              hipStream_t stream) {
  const float* x  = (const float*)d_in[0];
  const float* Wq = (const float*)d_in[1];
  const float* Wk = (const float*)d_in[2];
  const float* Wv = (const float*)d_in[3];
  const float* Wo = (const float*)d_in[4];
  float* out = (float*)d_out;
  char* ws = (char*)d_ws;
  u16* Xb   = (u16*)(ws);                        // 16 MiB  bf16 x        [4096][2048]
  u16* Wcat = (u16*)(ws + (16ull << 20));        // 12 MiB  [WqT|WkT|WvT] = [3072][2048]
  u16* WqT  = Wcat;
  u16* WkT  = (u16*)(ws + (24ull << 20));
  u16* WvT  = (u16*)(ws + (26ull << 20));
  u16* WoT  = (u16*)(ws + (28ull << 20));        //  8 MiB
  u16* QKVb = (u16*)(ws + (36ull << 20));        // 24 MiB  [4096][3072]  Q|K|V proj
  u16* Vt   = (u16*)(ws + (60ull << 20));        //  4 MiB  V^T           [2][4][128][2048]
  u16* Ob   = (u16*)(ws + (64ull << 20));        // 16 MiB  attn out      [4096][16][128]
  u16* Kp   = (u16*)(ws + (80ull << 20));        //  4 MiB  K roped+packed[2][4][2048][128]
  float2* trig = (float2*)(ws + (84ull << 20));  //  1 MiB  RoPE cos/sin  [2048][64]

  static bool attr_set = false;
  if (!attr_set) {
    hipFuncSetAttribute((const void*)gemm256x192_qkv,
                        hipFuncAttributeMaxDynamicSharedMemorySize, 114688);
    hipFuncSetAttribute((const void*)gemm256x128_wo,
                        hipFuncAttributeMaxDynamicSharedMemorySize, 98304);
    attr_set = true;
  }

  dim3 tb32(32, 8);

  build_trig<<<dim3(S_ * 64 / 256), 256, 0, stream>>>(trig);

  convert_fp32_bf16<<<dim3(M_ * E_ / 4 / 256), 256, 0, stream>>>((const float4*)x, (uint2*)Xb, M_ * E_ / 4);

  transpose_conv_all<<<dim3(160, 64), tb32, 0, stream>>>(Wq, Wk, Wv, Wo, WqT, WkT, WvT, WoT);

  gemm256x192_qkv<<<dim3(16, 16), 512, 114688, stream>>>(Xb, Wcat, QKVb);

  rope_k_tv<<<dim3(4096 + 2048), 256, 0, stream>>>(QKVb, Kp, Vt, trig);

  attn_kernel<<<dim3(H_, 16, B_), 512, 0, stream>>>(QKVb, Kp, Vt, Ob, trig);

  gemm256x128_wo<<<dim3(2048 / 128, M_ / 256), 512, 98304, stream>>>(Ob, WoT, out);
}

// Round 14
// 268.587 us; speedup vs baseline: 1.2229x; 1.0217x over previous
//
#include <hip/hip_runtime.h>
#include <stdint.h>

#define B_ 2
#define S_ 2048
#define E_ 2048
#define H_ 16
#define KV_ 4
#define D_ 128
#define G_ (H_ / KV_)
#define M_ (B_ * S_)   // 4096 rows (b*s)
#define NQKV 3072      // Q 2048 | K 512 | V 512 (concatenated projection)

typedef unsigned short u16;
typedef unsigned int u32;
typedef __bf16 bf16x8 __attribute__((ext_vector_type(8)));
typedef float f32x4 __attribute__((ext_vector_type(4)));

__device__ __forceinline__ u16 f2bf(float f) {
  __bf16 h = (__bf16)f;            // v_cvt RNE
  return *(u16*)&h;
}
__device__ __forceinline__ float bf2f(u16 x) {
  return __uint_as_float(((u32)x) << 16);
}

// async global->LDS, 16B per lane; LDS dest = wave-uniform base + lane*16
__device__ __forceinline__ void gload_lds16(const u16* g, u16* lds) {
  __builtin_amdgcn_global_load_lds((const __attribute__((address_space(1))) u32*)g,
                                   (__attribute__((address_space(3))) u32*)lds,
                                   16, 0, 0);
}

// ---------------- fused preprocessing: trig table + x->bf16 + all 4 weight transposes ----------------
// blocks [0,512):        trig[s*64+d] = (cos,sin)(s * 10000^(-d/64))
// blocks [512,8704):     x fp32 -> bf16 (float4 -> 2x packed bf16)
// blocks [8704,18944):   32x32 LDS transpose of Wq|Wk|Wv|Wo fp32 -> bf16 N-major
// All three read only kernel inputs; outputs disjoint -> no ordering hazard.
__global__ __launch_bounds__(256) void preprocess_all(const float4* __restrict__ x4,
                                                      uint2* __restrict__ xb,
                                                      const float* __restrict__ Wq,
                                                      const float* __restrict__ Wk,
                                                      const float* __restrict__ Wv,
                                                      const float* __restrict__ Wo,
                                                      u16* __restrict__ WqT,
                                                      u16* __restrict__ WkT,
                                                      u16* __restrict__ WvT,
                                                      u16* __restrict__ WoT,
                                                      float2* __restrict__ tbl) {
  __shared__ float tile[32][33];
  const int bx = blockIdx.x;
  const int tid = threadIdx.x;
  if (bx < 512) {
    int i = bx * 256 + tid;                      // [0, 2048*64)
    int d = i & 63, s = i >> 6;
    float ang = (float)s * expf(-0.14391156831212787f * (float)d);
    float sn, cs;
    sincosf(ang, &sn, &cs);
    tbl[i] = make_float2(cs, sn);
  } else if (bx < 8704) {
    int i = (bx - 512) * 256 + tid;              // [0, M_*E_/4)
    float4 v = x4[i];
    uint2 r;
    r.x = (u32)f2bf(v.x) | ((u32)f2bf(v.y) << 16);
    r.y = (u32)f2bf(v.z) | ((u32)f2bf(v.w) << 16);
    xb[i] = r;
  } else {
    int i = bx - 8704;                           // [0, 160*64)
    int nxp = i % 160;                           // which n-tile across the 4 weights
    int k0 = (i / 160) * 32;
    const float* W;
    u16* Wt;
    int Ndim, nx;
    if (nxp < 64)       { W = Wq; Wt = WqT; Ndim = 2048; nx = nxp; }
    else if (nxp < 80)  { W = Wk; Wt = WkT; Ndim = 512;  nx = nxp - 64; }
    else if (nxp < 96)  { W = Wv; Wt = WvT; Ndim = 512;  nx = nxp - 80; }
    else                { W = Wo; Wt = WoT; Ndim = 2048; nx = nxp - 96; }
    int n0 = nx * 32;
    int tx = tid & 31, ty = tid >> 5;
#pragma unroll
    for (int k = 0; k < 4; k++) {
      int r = ty + k * 8;
      tile[r][tx] = W[(size_t)(k0 + r) * Ndim + n0 + tx];
    }
    __syncthreads();
#pragma unroll
    for (int k = 0; k < 4; k++) {
      int r = ty + k * 8;
      Wt[(size_t)(n0 + r) * 2048 + k0 + tx] = f2bf(tile[tx][r]);
    }
  }
}

// ---------------- fused: RoPE K repack (table) + V transpose, one launch ----------------
__global__ __launch_bounds__(256) void rope_k_tv(const u16* __restrict__ QKV,
                                                 u16* __restrict__ Kp,
                                                 u16* __restrict__ Vt,
                                                 const float2* __restrict__ tbl) {
  __shared__ u16 tile[32][33];
  int bx = blockIdx.x;
  int tid = threadIdx.x;
  if (bx < 4096) {
    int idx = bx * 256 + tid;                    // [0, M_*KV_*64)
    int d = idx & 63;
    int rem = idx >> 6;
    int kv = rem & (KV_ - 1);
    int row = rem >> 2;
    int b = row >> 11;                           // row / S_
    int spos = row & (S_ - 1);
    size_t src = (size_t)row * NQKV + 2048 + kv * D_ + d;
    float x0 = bf2f(QKV[src]);
    float x1 = bf2f(QKV[src + 64]);
    float2 t = tbl[(spos << 6) + d];
    size_t dst = ((size_t)((b * KV_ + kv) * S_ + spos)) * D_ + d;
    Kp[dst]      = f2bf(x0 * t.x - x1 * t.y);
    Kp[dst + 64] = f2bf(x1 * t.x + x0 * t.y);
  } else {
    int i = bx - 4096;                           // [0, 2048)
    int s0 = (i & 63) * 32;                      // 64 s-tiles
    int d0 = ((i >> 6) & 3) * 32;                // 4 d-tiles
    int bkv = i >> 8;                            // 8 (b,kv)
    int b = bkv / KV_, kv = bkv % KV_;
    int tx = tid & 31, ty = tid >> 5;
#pragma unroll
    for (int k = 0; k < 4; k++) {
      int r = ty + k * 8;  // s within tile
      tile[r][tx] = QKV[(size_t)(b * S_ + s0 + r) * NQKV + 2560 + kv * D_ + d0 + tx];
    }
    __syncthreads();
#pragma unroll
    for (int k = 0; k < 4; k++) {
      int r = ty + k * 8;  // d within tile
      Vt[((size_t)(b * KV_ + kv) * D_ + d0 + r) * S_ + s0 + tx] = tile[tx][r];
    }
  }
}

// =====================================================================
// 256x192 4-phase bf16 GEMM for the fused QKV projection (verified r9).
// =====================================================================
__global__ __launch_bounds__(512, 2) void gemm256x192_qkv(const u16* __restrict__ A,
                                                          const u16* __restrict__ Bt,
                                                          u16* __restrict__ C) {
  extern __shared__ __align__(16) u16 smem[];   // 57344 u16 = 112 KiB
  const int Kdim = 2048;
  const int m0 = blockIdx.y * 256, n0 = blockIdx.x * 192;
  const int tid  = threadIdx.x;
  const int lane = tid & 63;
  const int wave = tid >> 6;          // 0..7
  const int wm   = wave >> 2;         // 0..1  M-half
  const int wn   = wave & 3;          // 0..3  N-quarter (48 cols each)
  const int quad = lane >> 4, lm = lane & 15;

  int soffA[2], sldbA[2];
#pragma unroll
  for (int i = 0; i < 2; i++) {
    int cc  = i * 512 + tid;
    int row = cc >> 3;
    int q   = (cc & 7) ^ (row & 7);
    soffA[i] = row * Kdim + q * 8;
    sldbA[i] = (i * 512 + wave * 64) * 8;
  }
  const int rowB = tid >> 3;
  const int soffB = rowB * Kdim + (((tid & 7) ^ (rowB & 7)) * 8);
  const int sldbB = wave * 512;
  auto STAGE_A = [&](const u16* g, u16* l) {
    gload_lds16(g + soffA[0], l + sldbA[0]);
    gload_lds16(g + soffA[1], l + sldbA[1]);
  };
  auto STAGE_B = [&](const u16* g, u16* l) {
    gload_lds16(g + soffB, l + sldbB);
  };

  int cs0 = ((0 + quad) ^ (lm & 7)) * 8;
  int cs1 = ((4 + quad) ^ (lm & 7)) * 8;

  const u16* Ag = A  + (size_t)m0 * Kdim;
  const u16* Bg = Bt + (size_t)n0 * Kdim;
  const size_t hstepA = (size_t)128 * Kdim;
  const size_t tstepB = (size_t)64 * Kdim;

  f32x4 acc[8][3];
  f32x4 zero = {0.f, 0.f, 0.f, 0.f};
#pragma unroll
  for (int m = 0; m < 8; m++)
#pragma unroll
    for (int n = 0; n < 3; n++) acc[m][n] = zero;

  int bthird[3], brow[3];
#pragma unroll
  for (int nt = 0; nt < 3; nt++) {
    int R = wn * 48 + nt * 16;
    bthird[nt] = R >> 6;
    brow[nt] = (R & 63) + lm;
  }

  const int NKT = Kdim >> 6;   // 32

  STAGE_B(Bg,                    smem + 32768 + 0 * 4096);
  STAGE_A(Ag,                    smem + 0 * 8192);
  STAGE_A(Ag + hstepA,           smem + 1 * 8192);
  STAGE_B(Bg + tstepB,           smem + 32768 + 1 * 4096);
  STAGE_B(Bg + 2 * tstepB,       smem + 32768 + 2 * 4096);
  STAGE_B(Bg + 64,               smem + 32768 + 3 * 4096);
  STAGE_A(Ag + 64,               smem + 2 * 8192);
  STAGE_A(Ag + hstepA + 64,      smem + 3 * 8192);
  asm volatile("s_waitcnt vmcnt(5)" ::: "memory");
  __builtin_amdgcn_s_barrier();

  for (int kt = 0; kt < NKT; ++kt) {
    const int cur = kt & 1;
    const u16* regA  = smem + (cur * 2 + wm) * 8192;
    const u16* regB3 = smem + 32768 + cur * 3 * 4096;
    bf16x8 af[4][2], bf[3][2];

    // ---------- phase 0 ----------
#pragma unroll
    for (int nt = 0; nt < 3; nt++) {
      const u16* p = regB3 + bthird[nt] * 4096 + brow[nt] * 64;
      bf[nt][0] = *(const bf16x8*)(p + cs0);
      bf[nt][1] = *(const bf16x8*)(p + cs1);
    }
#pragma unroll
    for (int m = 0; m < 4; m++) {
      af[m][0] = *(const bf16x8*)(regA + (m * 16 + lm) * 64 + cs0);
      af[m][1] = *(const bf16x8*)(regA + (m * 16 + lm) * 64 + cs1);
    }
    if (kt + 1 < NKT) {
      const u16* bn = Bg + (size_t)(kt + 1) * 64;
      u16* sb = smem + 32768 + ((cur ^ 1) * 3) * 4096;
      STAGE_B(bn + tstepB,     sb + 1 * 4096);
      STAGE_B(bn + 2 * tstepB, sb + 2 * 4096);
    }
    asm volatile("s_waitcnt lgkmcnt(0)" ::: "memory");
    __builtin_amdgcn_s_barrier();
    __builtin_amdgcn_s_setprio(1);
#pragma unroll
    for (int m = 0; m < 4; m++)
#pragma unroll
      for (int n = 0; n < 2; n++) {
        acc[m][n] = __builtin_amdgcn_mfma_f32_16x16x32_bf16(af[m][0], bf[n][0], acc[m][n], 0, 0, 0);
        acc[m][n] = __builtin_amdgcn_mfma_f32_16x16x32_bf16(af[m][1], bf[n][1], acc[m][n], 0, 0, 0);
      }
    __builtin_amdgcn_s_setprio(0);
    __builtin_amdgcn_s_barrier();

    // ---------- phase 1 ----------
    if (kt + 2 < NKT)
      STAGE_B(Bg + (size_t)(kt + 2) * 64, smem + 32768 + (cur * 3 + 0) * 4096);
    __builtin_amdgcn_s_barrier();
    __builtin_amdgcn_s_setprio(1);
#pragma unroll
    for (int m = 0; m < 4; m++) {
      acc[m][2] = __builtin_amdgcn_mfma_f32_16x16x32_bf16(af[m][0], bf[2][0], acc[m][2], 0, 0, 0);
      acc[m][2] = __builtin_amdgcn_mfma_f32_16x16x32_bf16(af[m][1], bf[2][1], acc[m][2], 0, 0, 0);
    }
    __builtin_amdgcn_s_setprio(0);
    __builtin_amdgcn_s_barrier();

    // ---------- phase 2 ----------
#pragma unroll
    for (int m = 0; m < 4; m++) {
      af[m][0] = *(const bf16x8*)(regA + ((m + 4) * 16 + lm) * 64 + cs0);
      af[m][1] = *(const bf16x8*)(regA + ((m + 4) * 16 + lm) * 64 + cs1);
    }
    asm volatile("s_waitcnt lgkmcnt(0)" ::: "memory");
    __builtin_amdgcn_s_barrier();
    __builtin_amdgcn_s_setprio(1);
#pragma unroll
    for (int m = 0; m < 4; m++)
#pragma unroll
      for (int n = 0; n < 2; n++) {
        acc[m + 4][n] = __builtin_amdgcn_mfma_f32_16x16x32_bf16(af[m][0], bf[n][0], acc[m + 4][n], 0, 0, 0);
        acc[m + 4][n] = __builtin_amdgcn_mfma_f32_16x16x32_bf16(af[m][1], bf[n][1], acc[m + 4][n], 0, 0, 0);
      }
    __builtin_amdgcn_s_setprio(0);
    __builtin_amdgcn_s_barrier();

    // ---------- phase 3 ----------
    if (kt + 2 < NKT) {
      STAGE_A(Ag + (size_t)(kt + 2) * 64,          smem + (cur * 2 + 0) * 8192);
      STAGE_A(Ag + hstepA + (size_t)(kt + 2) * 64, smem + (cur * 2 + 1) * 8192);
    }
    __builtin_amdgcn_s_setprio(1);
#pragma unroll
    for (int m = 0; m < 4; m++) {
      acc[m + 4][2] = __builtin_amdgcn_mfma_f32_16x16x32_bf16(af[m][0], bf[2][0], acc[m + 4][2], 0, 0, 0);
      acc[m + 4][2] = __builtin_amdgcn_mfma_f32_16x16x32_bf16(af[m][1], bf[2][1], acc[m + 4][2], 0, 0, 0);
    }
    __builtin_amdgcn_s_setprio(0);
    asm volatile("s_waitcnt vmcnt(5)" ::: "memory");
    __builtin_amdgcn_s_barrier();
  }

#pragma unroll
  for (int m = 0; m < 8; m++) {
    const int row = m0 + wm * 128 + m * 16 + quad * 4;
#pragma unroll
    for (int n = 0; n < 3; n++) {
      const int col = n0 + wn * 48 + n * 16 + lm;
#pragma unroll
      for (int r = 0; r < 4; r++)
        C[(size_t)(row + r) * NQKV + col] = f2bf(acc[m][n][r]);
    }
  }
}

// =====================================================================
// 256x128-tile GEMM for Wo (verified round 8): grid (16,16) = 256 blocks.
// =====================================================================
__global__ __launch_bounds__(512, 2) void gemm256x128_wo(const u16* __restrict__ A,
                                                         const u16* __restrict__ Bt,
                                                         float* __restrict__ C) {
  extern __shared__ __align__(16) u16 smem[];   // 49152 u16 = 96 KiB
  const int Kdim = 2048, Ndim = 2048;
  const int m0 = blockIdx.y * 256, n0 = blockIdx.x * 128;
  const int tid  = threadIdx.x;
  const int lane = tid & 63;
  const int wave = tid >> 6;          // 0..7
  const int wm   = wave >> 2;
  const int wn   = wave & 3;
  const int bh   = wn >> 1;
  const int nb   = (wn & 1) * 32;
  const int quad = lane >> 4, lm = lane & 15;

  int soffA[2], sldbA[2];
#pragma unroll
  for (int i = 0; i < 2; i++) {
    int cc  = i * 512 + tid;
    int row = cc >> 3;
    int q   = (cc & 7) ^ (row & 7);
    soffA[i] = row * Kdim + q * 8;
    sldbA[i] = (i * 512 + wave * 64) * 8;
  }
  const int rowB = tid >> 3;
  const int soffB = rowB * Kdim + (((tid & 7) ^ (rowB & 7)) * 8);
  const int sldbB = wave * 512;
  auto STAGE_A = [&](const u16* g, u16* l) {
    gload_lds16(g + soffA[0], l + sldbA[0]);
    gload_lds16(g + soffA[1], l + sldbA[1]);
  };
  auto STAGE_B = [&](const u16* g, u16* l) {
    gload_lds16(g + soffB, l + sldbB);
  };

  int cs0 = ((0 + quad) ^ (lm & 7)) * 8;
  int cs1 = ((4 + quad) ^ (lm & 7)) * 8;

  const u16* Ag = A  + (size_t)m0 * Kdim;
  const u16* Bg = Bt + (size_t)n0 * Kdim;
  const size_t hstepA = (size_t)128 * Kdim;
  const size_t hstepB = (size_t)64 * Kdim;

  f32x4 acc[8][2];
  f32x4 zero = {0.f, 0.f, 0.f, 0.f};
#pragma unroll
  for (int m = 0; m < 8; m++) {
    acc[m][0] = zero;
    acc[m][1] = zero;
  }

  const int NKT = Kdim >> 6;   // 32

  STAGE_B(Bg,              smem + 32768 + 0 * 4096);
  STAGE_A(Ag,              smem + 0 * 8192);
  STAGE_A(Ag + hstepA,     smem + 1 * 8192);
  STAGE_B(Bg + hstepB,     smem + 32768 + 1 * 4096);
  STAGE_B(Bg + 64,         smem + 32768 + 2 * 4096);
  STAGE_A(Ag + 64,         smem + 2 * 8192);
  STAGE_A(Ag + hstepA + 64, smem + 3 * 8192);
  asm volatile("s_waitcnt vmcnt(5)" ::: "memory");
  __builtin_amdgcn_s_barrier();

  for (int kt = 0; kt < NKT; ++kt) {
    const int cur = kt & 1;
    const u16* regA = smem + (cur * 2 + wm) * 8192;
    const u16* regB = smem + 32768 + (cur * 2 + bh) * 4096;
    bf16x8 af[4][2], bf[2][2];

    // ---------- phase 0 ----------
#pragma unroll
    for (int n = 0; n < 2; n++) {
      bf[n][0] = *(const bf16x8*)(regB + (nb + n * 16 + lm) * 64 + cs0);
      bf[n][1] = *(const bf16x8*)(regB + (nb + n * 16 + lm) * 64 + cs1);
    }
#pragma unroll
    for (int m = 0; m < 4; m++) {
      af[m][0] = *(const bf16x8*)(regA + (m * 16 + lm) * 64 + cs0);
      af[m][1] = *(const bf16x8*)(regA + (m * 16 + lm) * 64 + cs1);
    }
    if (kt + 1 < NKT)
      STAGE_B(Bg + hstepB + (size_t)(kt + 1) * 64,
              smem + 32768 + (((kt + 1) & 1) * 2 + 1) * 4096);
    asm volatile("s_waitcnt lgkmcnt(0)" ::: "memory");
    __builtin_amdgcn_s_barrier();
    __builtin_amdgcn_s_setprio(1);
#pragma unroll
    for (int m = 0; m < 2; m++)
#pragma unroll
      for (int n = 0; n < 2; n++) {
        acc[m][n] = __builtin_amdgcn_mfma_f32_16x16x32_bf16(af[m][0], bf[n][0], acc[m][n], 0, 0, 0);
        acc[m][n] = __builtin_amdgcn_mfma_f32_16x16x32_bf16(af[m][1], bf[n][1], acc[m][n], 0, 0, 0);
      }
    __builtin_amdgcn_s_setprio(0);
    __builtin_amdgcn_s_barrier();

    // ---------- phase 1 ----------
    if (kt + 2 < NKT)
      STAGE_B(Bg + (size_t)(kt + 2) * 64, smem + 32768 + (cur * 2 + 0) * 4096);
    __builtin_amdgcn_s_barrier();
    __builtin_amdgcn_s_setprio(1);
#pragma unroll
    for (int m = 2; m < 4; m++)
#pragma unroll
      for (int n = 0; n < 2; n++) {
        acc[m][n] = __builtin_amdgcn_mfma_f32_16x16x32_bf16(af[m][0], bf[n][0], acc[m][n], 0, 0, 0);
        acc[m][n] = __builtin_amdgcn_mfma_f32_16x16x32_bf16(af[m][1], bf[n][1], acc[m][n], 0, 0, 0);
      }
    __builtin_amdgcn_s_setprio(0);
    __builtin_amdgcn_s_barrier();

    // ---------- phase 2 ----------
#pragma unroll
    for (int m = 0; m < 4; m++) {
      af[m][0] = *(const bf16x8*)(regA + ((m + 4) * 16 + lm) * 64 + cs0);
      af[m][1] = *(const bf16x8*)(regA + ((m + 4) * 16 + lm) * 64 + cs1);
    }
    asm volatile("s_waitcnt lgkmcnt(0)" ::: "memory");
    __builtin_amdgcn_s_barrier();
    __builtin_amdgcn_s_setprio(1);
#pragma unroll
    for (int m = 0; m < 2; m++)
#pragma unroll
      for (int n = 0; n < 2; n++) {
        acc[m + 4][n] = __builtin_amdgcn_mfma_f32_16x16x32_bf16(af[m][0], bf[n][0], acc[m + 4][n], 0, 0, 0);
        acc[m + 4][n] = __builtin_amdgcn_mfma_f32_16x16x32_bf16(af[m][1], bf[n][1], acc[m + 4][n], 0, 0, 0);
      }
    __builtin_amdgcn_s_setprio(0);
    __builtin_amdgcn_s_barrier();

    // ---------- phase 3 ----------
    if (kt + 2 < NKT) {
      STAGE_A(Ag + (size_t)(kt + 2) * 64,          smem + (cur * 2 + 0) * 8192);
      STAGE_A(Ag + hstepA + (size_t)(kt + 2) * 64, smem + (cur * 2 + 1) * 8192);
    }
    __builtin_amdgcn_s_setprio(1);
#pragma unroll
    for (int m = 2; m < 4; m++)
#pragma unroll
      for (int n = 0; n < 2; n++) {
        acc[m + 4][n] = __builtin_amdgcn_mfma_f32_16x16x32_bf16(af[m][0], bf[n][0], acc[m + 4][n], 0, 0, 0);
        acc[m + 4][n] = __builtin_amdgcn_mfma_f32_16x16x32_bf16(af[m][1], bf[n][1], acc[m + 4][n], 0, 0, 0);
      }
    __builtin_amdgcn_s_setprio(0);
    asm volatile("s_waitcnt vmcnt(5)" ::: "memory");
    __builtin_amdgcn_s_barrier();
  }

#pragma unroll
  for (int m = 0; m < 8; m++) {
    const int row = m0 + wm * 128 + m * 16 + quad * 4;
#pragma unroll
    for (int n = 0; n < 2; n++) {
      const int col = n0 + wn * 32 + n * 16 + lm;
#pragma unroll
      for (int r = 0; r < 4; r++)
        C[(size_t)(row + r) * Ndim + col] = acc[m][n][r];
    }
  }
}

// ---------------- causal GQA flash attention, v15 (verified r13, unchanged) ----------------
__global__ __launch_bounds__(512, 4) void attn_kernel(const u16* __restrict__ Q,
                                                      const u16* __restrict__ Kp,
                                                      const u16* __restrict__ Vt,
                                                      u16* __restrict__ O,
                                                      const float2* __restrict__ tbl) {
  __shared__ __align__(16) u16 Ksh[2][64 * 128];   // 2 x 16 KB
  __shared__ __align__(16) u16 Vsh[128 * 64];      // 16 KB (single)
  __shared__ __align__(16) u16 Psh[8][16 * 64];    // 16 KB, per-wave

  const int tid = threadIdx.x;
  const int lane = tid & 63;
  const int wave = tid >> 6;                       // 0..7
  const int quad = lane >> 4, lm = lane & 15;
  const int b = blockIdx.z, h = blockIdx.x;        // h on x for XCD locality
  const int y = blockIdx.y;                        // 0..15
  const int kh = h / G_;
  const int qi = b ? y : (15 - y);                 // co-residency pairing

  const u16* Kbase = Kp + (size_t)(b * KV_ + kh) * S_ * D_;
  const u16* Vbase = Vt + (size_t)(b * KV_ + kh) * D_ * S_;
  u16* pw = &Psh[wave][0];

  // DMA source offsets (XOR-swizzled); 1024 chunks/tile over 512 threads -> 2 each
  int offK[2], offV[2], ldsOff[2];
#pragma unroll
  for (int i = 0; i < 2; i++) {
    int idx = (wave * 2 + i) * 64 + lane;          // [0,1024) 16B-chunk id
    int rK = idx >> 4;
    int cK = (idx & 15) ^ (rK & 7);
    offK[i] = rK * 128 + cK * 8;
    int rV = idx >> 3;
    int cV = (idx & 7) ^ (rV & 7);
    offV[i] = rV * S_ + cV * 8;
    ldsOff[i] = (wave * 2 + i) * 512;
  }

  bf16x8 onesb;
#pragma unroll
  for (int j = 0; j < 8; j++) onesb[j] = (__bf16)1.0f;

  const int sq0 = qi * 128;
  const int nT = 2 * qi + 2;                       // 64-key tiles covering sq0+128
  const int wrow = sq0 + wave * 16;                // this wave's first Q row

  // ---- Q fragment load + fused table-RoPE + 1/sqrt(D) scale ----
  const int spos = wrow + lm;                      // sequence position (< S_)
  const u16* qptr = Q + (size_t)(b * S_ + spos) * NQKV + h * D_;
  bf16x8 qf[4];
#pragma unroll
  for (int ks = 0; ks < 2; ks++) {
    bf16x8 a = *(const bf16x8*)(qptr + ks * 32 + quad * 8);
    bf16x8 c = *(const bf16x8*)(qptr + (ks + 2) * 32 + quad * 8);
#pragma unroll
    for (int j = 0; j < 8; j++) {
      int d = ks * 32 + quad * 8 + j;
      float2 t = tbl[(spos << 6) + d];
      float x0 = (float)a[j], x1 = (float)c[j];
      const float scale = 0.08838834764831845f;
      qf[ks][j]     = (__bf16)((x0 * t.x - x1 * t.y) * scale);
      qf[ks + 2][j] = (__bf16)((x1 * t.x + x0 * t.y) * scale);
    }
  }

  f32x4 o[8];
  f32x4 lacc = {0.f, 0.f, 0.f, 0.f};
#pragma unroll
  for (int i = 0; i < 8; i++) o[i] = f32x4{0.f, 0.f, 0.f, 0.f};

  // prologue: DMA K(0) into buffer 0
#pragma unroll
  for (int i = 0; i < 2; i++)
    gload_lds16(Kbase + offK[i], &Ksh[0][ldsOff[i]]);

  for (int t = 0; t < nT; t++) {
    const int sk0 = t << 6;
    const bool act = (sk0 <= wrow + 15);           // skip fully-masked tiles

    __builtin_amdgcn_s_barrier();   // (#1) prev iter fully done: Vsh + Ksh[(t+1)&1] free

    // issue V(t) first, then K(t+1): vmcnt counts below depend on this order
#pragma unroll
    for (int i = 0; i < 2; i++)
      gload_lds16(Vbase + sk0 + offV[i], &Vsh[ldsOff[i]]);
    if (t + 1 < nT) {
      const u16* kg = Kbase + (size_t)(t + 1) * 64 * 128;
      u16* kb_next = &Ksh[(t + 1) & 1][0];
#pragma unroll
      for (int i = 0; i < 2; i++)
        gload_lds16(kg + offK[i], kb_next + ldsOff[i]);
      asm volatile("s_waitcnt vmcnt(4)" ::: "memory");  // K(t) resident (own ops)
    } else {
      asm volatile("s_waitcnt vmcnt(2)" ::: "memory");  // K(t) resident; V(t) in flight
    }

    __builtin_amdgcn_s_barrier();   // (#2) K(t) resident for ALL waves
    __builtin_amdgcn_sched_barrier(0);

    if (act) {
      // S = Q K^T (scale prefolded into Q)
      const u16* kbuf = &Ksh[t & 1][0];
      f32x4 sc[4];
#pragma unroll
      for (int nt = 0; nt < 4; nt++) sc[nt] = f32x4{0.f, 0.f, 0.f, 0.f};
      __builtin_amdgcn_s_setprio(1);
#pragma unroll
      for (int ks = 0; ks < 4; ks++) {
#pragma unroll
        for (int nt = 0; nt < 4; nt++) {
          int R = nt * 16 + lm;
          bf16x8 kb = *(const bf16x8*)(kbuf + R * 128 + (((ks * 4 + quad) ^ (R & 7)) * 8));
          sc[nt] = __builtin_amdgcn_mfma_f32_16x16x32_bf16(qf[ks], kb, sc[nt], 0, 0, 0);
        }
      }
      __builtin_amdgcn_s_setprio(0);
      // P = exp(S); causal select only on the boundary tile (wave-uniform nm)
      const bool nm = (sk0 + 63 > wrow);
#pragma unroll
      for (int nt = 0; nt < 4; nt++)
#pragma unroll
        for (int r = 0; r < 4; r++) {
          float p = __expf(sc[nt][r]);
          if (nm) {
            int kc = sk0 + nt * 16 + lm;
            int qr = wrow + quad * 4 + r;
            p = (kc > qr) ? 0.f : p;
          }
          sc[nt][r] = p;
        }
      // P: C-layout -> per-wave swizzled LDS (A-layout source for PV)
#pragma unroll
      for (int nt = 0; nt < 4; nt++)
#pragma unroll
        for (int r = 0; r < 4; r++) {
          int p = quad * 4 + r;
          int c = nt * 2 + (lm >> 3);
          pw[p * 64 + ((c ^ (p & 7)) * 8) + (lm & 7)] = f2bf(sc[nt][r]);
        }
    }

    if (t + 1 < nT) {
      asm volatile("s_waitcnt vmcnt(2)" ::: "memory");  // V(t) resident; K(t+1) in flight
    } else {
      asm volatile("s_waitcnt vmcnt(0)" ::: "memory");  // V(t) resident
    }
    __builtin_amdgcn_s_barrier();   // (#3) V(t) resident for ALL waves
    __builtin_amdgcn_sched_barrier(0);

    if (act) {
      // O += P @ V ; l += P @ ones   (per-wave Psh: within-wave lgkm dep only)
      __builtin_amdgcn_s_setprio(1);
#pragma unroll
      for (int ks = 0; ks < 2; ks++) {
        int pr = lm;
        bf16x8 pa = *(const bf16x8*)(pw + pr * 64 + (((ks * 4 + quad) ^ (pr & 7)) * 8));
        lacc = __builtin_amdgcn_mfma_f32_16x16x32_bf16(pa, onesb, lacc, 0, 0, 0);
#pragma unroll
        for (int d8 = 0; d8 < 8; d8++) {
          int R = d8 * 16 + lm;
          bf16x8 vb = *(const bf16x8*)(Vsh + R * 64 + (((ks * 4 + quad) ^ (R & 7)) * 8));
          o[d8] = __builtin_amdgcn_mfma_f32_16x16x32_bf16(pa, vb, o[d8], 0, 0, 0);
        }
      }
      __builtin_amdgcn_s_setprio(0);
    }
  }

  float inv[4];
#pragma unroll
  for (int r = 0; r < 4; r++) inv[r] = 1.0f / lacc[r];
#pragma unroll
  for (int d8 = 0; d8 < 8; d8++)
#pragma unroll
    for (int r = 0; r < 4; r++) {
      int srow = wrow + quad * 4 + r;
      O[((size_t)(b * S_ + srow) * H_ + h) * D_ + d8 * 16 + lm] = f2bf(o[d8][r] * inv[r]);
    }
}

extern "C" void kernel_launch(void* const* d_in, const int* in_sizes, int n_in,
                              void* d_out, int out_size, void* d_ws, size_t ws_size,
                              hipStream_t stream) {
  const float* x  = (const float*)d_in[0];
  const float* Wq = (const float*)d_in[1];
  const float* Wk = (const float*)d_in[2];
  const float* Wv = (const float*)d_in[3];
  const float* Wo = (const float*)d_in[4];
  float* out = (float*)d_out;
  char* ws = (char*)d_ws;
  u16* Xb   = (u16*)(ws);                        // 16 MiB  bf16 x        [4096][2048]
  u16* Wcat = (u16*)(ws + (16ull << 20));        // 12 MiB  [WqT|WkT|WvT] = [3072][2048]
  u16* WqT  = Wcat;
  u16* WkT  = (u16*)(ws + (24ull << 20));
  u16* WvT  = (u16*)(ws + (26ull << 20));
  u16* WoT  = (u16*)(ws + (28ull << 20));        //  8 MiB
  u16* QKVb = (u16*)(ws + (36ull << 20));        // 24 MiB  [4096][3072]  Q|K|V proj
  u16* Vt   = (u16*)(ws + (60ull << 20));        //  4 MiB  V^T           [2][4][128][2048]
  u16* Ob   = (u16*)(ws + (64ull << 20));        // 16 MiB  attn out      [4096][16][128]
  u16* Kp   = (u16*)(ws + (80ull << 20));        //  4 MiB  K roped+packed[2][4][2048][128]
  float2* trig = (float2*)(ws + (84ull << 20));  //  1 MiB  RoPE cos/sin  [2048][64]

  static bool attr_set = false;
  if (!attr_set) {
    hipFuncSetAttribute((const void*)gemm256x192_qkv,
                        hipFuncAttributeMaxDynamicSharedMemorySize, 114688);
    hipFuncSetAttribute((const void*)gemm256x128_wo,
                        hipFuncAttributeMaxDynamicSharedMemorySize, 98304);
    attr_set = true;
  }

  preprocess_all<<<dim3(512 + 8192 + 160 * 64), 256, 0, stream>>>(
      (const float4*)x, (uint2*)Xb, Wq, Wk, Wv, Wo, WqT, WkT, WvT, WoT, trig);

  gemm256x192_qkv<<<dim3(16, 16), 512, 114688, stream>>>(Xb, Wcat, QKVb);

  rope_k_tv<<<dim3(4096 + 2048), 256, 0, stream>>>(QKVb, Kp, Vt, trig);

  attn_kernel<<<dim3(H_, 16, B_), 512, 0, stream>>>(QKVb, Kp, Vt, Ob, trig);

  gemm256x128_wo<<<dim3(2048 / 128, M_ / 256), 512, 98304, stream>>>(Ob, WoT, out);
}